// Round 1
// baseline (533.249 us; speedup 1.0000x reference)
//
#include <hip/hip_runtime.h>
#include <hip/hip_bf16.h>

#define NTOK   16384
#define INF    1024
#define OUTF   4096
#define NBLK   16
#define BLKSZ  256
#define KTOP   4
#define PADROWS 67584  /* 65536 + 16*128 */

typedef short bf16x8 __attribute__((ext_vector_type(8)));
typedef float f32x4 __attribute__((ext_vector_type(4)));

__device__ __forceinline__ unsigned short f2bf(float f) {
  unsigned u = __float_as_uint(f);
  u += 0x7FFFu + ((u >> 16) & 1u);
  return (unsigned short)(u >> 16);
}

__device__ __forceinline__ void load_lds16(const void* g, void* l) {
  __builtin_amdgcn_global_load_lds(
      (const __attribute__((address_space(1))) unsigned int*)g,
      (__attribute__((address_space(3))) unsigned int*)l, 16, 0, 0);
}

// ---------------- zero counts + list pad ----------------
__global__ void k_zero(unsigned* __restrict__ list32, unsigned* __restrict__ counts) {
  int i = blockIdx.x * 256 + threadIdx.x;
  if (i < 33792) list32[i] = 0;            // 67584 u16 entries
  else if (i < 33808) counts[i - 33792] = 0;
}

// ---------------- fp32->bf16 conversion of x, w1, w2 ----------------
__global__ __launch_bounds__(256) void k_convert(
    const float* __restrict__ x, const float* __restrict__ w1,
    const float* __restrict__ w2, unsigned short* __restrict__ xb,
    unsigned short* __restrict__ w1b, unsigned short* __restrict__ w2b) {
  const size_t stride = (size_t)gridDim.x * 256;
  for (size_t i = (size_t)blockIdx.x * 256 + threadIdx.x; i < 6291456; i += stride) {
    const float4* src; ushort4* dst; size_t idx;
    if (i < 4194304)      { src = (const float4*)x;  dst = (ushort4*)xb;  idx = i; }
    else if (i < 5242880) { src = (const float4*)w1; dst = (ushort4*)w1b; idx = i - 4194304; }
    else                  { src = (const float4*)w2; dst = (ushort4*)w2b; idx = i - 5242880; }
    float4 v = src[idx];
    ushort4 o;
    o.x = f2bf(v.x); o.y = f2bf(v.y); o.z = f2bf(v.z); o.w = f2bf(v.w);
    dst[idx] = o;
  }
}

// ---------------- router: logits (f64 accum), top-4, counts ----------------
__global__ __launch_bounds__(256) void k_router(
    const float* __restrict__ x, const float* __restrict__ rw,
    const float* __restrict__ rb, unsigned* __restrict__ tok_blocks,
    unsigned* __restrict__ counts) {
  __shared__ float4 rwl[4096];  // full router_w [16][1024] fp32 = 64KB
  const int tid = threadIdx.x;
  const float4* rw4 = (const float4*)rw;
  for (int i = tid; i < 4096; i += 256) rwl[i] = rw4[i];
  __syncthreads();

  const int n = blockIdx.x * 256 + tid;
  double p[16];
#pragma unroll
  for (int j = 0; j < 16; ++j) p[j] = (double)rb[j];
  const float4* xr = (const float4*)(x + (size_t)n * INF);
  for (int d4 = 0; d4 < 256; ++d4) {
    const float4 xv = xr[d4];
#pragma unroll
    for (int j = 0; j < 16; ++j) {
      const float4 wv = rwl[j * 256 + d4];
      p[j] = fma((double)xv.x, (double)wv.x, p[j]);
      p[j] = fma((double)xv.y, (double)wv.y, p[j]);
      p[j] = fma((double)xv.z, (double)wv.z, p[j]);
      p[j] = fma((double)xv.w, (double)wv.w, p[j]);
    }
  }
  // rank: # of j2 strictly better (ties -> lower index wins, matching lax.top_k)
  unsigned packed = 0;
#pragma unroll
  for (int j = 0; j < 16; ++j) {
    int r = 0;
#pragma unroll
    for (int j2 = 0; j2 < 16; ++j2)
      r += (int)((p[j2] > p[j]) | ((p[j2] == p[j]) & (j2 < j)));
    if (r < KTOP) packed |= (unsigned)j << (8 * r);
  }
  tok_blocks[n] = packed;

  const int lane = tid & 63;
  for (int b = 0; b < 16; ++b) {
    bool sel = ((packed & 15u) == (unsigned)b) | (((packed >> 8) & 15u) == (unsigned)b) |
               (((packed >> 16) & 15u) == (unsigned)b) | (((packed >> 24) & 15u) == (unsigned)b);
    unsigned long long m = __ballot(sel);
    if (m) {
      int leader = __ffsll((unsigned long long)m) - 1;
      if (lane == leader) atomicAdd(&counts[b], (unsigned)__popcll(m));
    }
  }
}

// ---------------- scan: padded offsets + cursors ----------------
__global__ void k_scan(const unsigned* __restrict__ counts, unsigned* __restrict__ off,
                       unsigned* __restrict__ cursors) {
  if (threadIdx.x == 0 && blockIdx.x == 0) {
    unsigned o = 0;
    for (int i = 0; i < 16; ++i) {
      off[i] = o; cursors[i] = o;
      o += (counts[i] + 127u) & ~127u;
    }
    off[16] = o;
  }
}

// ---------------- build per-block token lists ----------------
__global__ __launch_bounds__(256) void k_build(
    const unsigned* __restrict__ tok_blocks, unsigned* __restrict__ cursors,
    unsigned short* __restrict__ list) {
  const int n = blockIdx.x * 256 + threadIdx.x;
  const unsigned packed = tok_blocks[n];
  const int lane = threadIdx.x & 63;
  for (int b = 0; b < 16; ++b) {
    int r = -1;
#pragma unroll
    for (int q = 0; q < 4; ++q)
      if (((packed >> (8 * q)) & 15u) == (unsigned)b) r = q;
    unsigned long long m = __ballot(r >= 0);
    if (m) {
      int leader = __ffsll((unsigned long long)m) - 1;
      unsigned base = 0;
      if (lane == leader) base = atomicAdd(&cursors[b], (unsigned)__popcll(m));
      base = (unsigned)__shfl((int)base, leader);
      if (r >= 0) {
        unsigned pos = base + (unsigned)__popcll(m & ((1ull << lane) - 1ull));
        list[pos] = (unsigned short)(n | (r << 14));
      }
    }
  }
}

// ---------------- out = b2 broadcast ----------------
__global__ __launch_bounds__(256) void k_init_out(const float* __restrict__ b2,
                                                  float* __restrict__ out) {
  const size_t stride = (size_t)gridDim.x * 256;
  const float4* b24 = (const float4*)b2;
  float4* out4 = (float4*)out;
  for (size_t i = (size_t)blockIdx.x * 256 + threadIdx.x; i < 4194304; i += stride)
    out4[i] = b24[i & 255];
}

// ---------------- fc1: h = relu(Xg @ W1blk^T + b1) -> hg (bf16) ----------------
__global__ __launch_bounds__(256, 2) void k_fc1(
    const unsigned short* __restrict__ xb, const unsigned short* __restrict__ w1b,
    const float* __restrict__ b1, const unsigned short* __restrict__ list,
    const unsigned* __restrict__ counts, const unsigned* __restrict__ off,
    unsigned short* __restrict__ hg) {
  const int bid = blockIdx.x;
  const int blk = bid >> 7;
  const int tile = bid & 127;
  const unsigned cnt = counts[blk];
  if ((unsigned)(tile * 128) >= cnt) return;
  const unsigned goff = off[blk] + tile * 128;

  __shared__ __align__(16) unsigned short As[128 * 64];
  __shared__ __align__(16) unsigned short Bs[256 * 64];
  __shared__ unsigned toks[128];

  const int tid = threadIdx.x;
  const int lane = tid & 63;
  const int wid = tid >> 6;
  const int wr = wid >> 1, wc = wid & 1;

  if (tid < 128) toks[tid] = list[goff + tid] & 0x3FFFu;
  __syncthreads();

  unsigned tokr[4]; int arow[4];
#pragma unroll
  for (int r = 0; r < 4; ++r) { arow[r] = (r * 256 + tid) >> 3; tokr[r] = toks[arow[r]]; }
  const int asl = tid & 7;

  f32x4 acc[4][8] = {};

  for (int k0 = 0; k0 < 1024; k0 += 64) {
    __syncthreads();
#pragma unroll
    for (int r = 0; r < 4; ++r) {
      const int kcs = asl ^ (arow[r] & 7);
      load_lds16(xb + (size_t)tokr[r] * INF + k0 + kcs * 8,
                 (char*)As + (r * 256 + wid * 64) * 16);
    }
#pragma unroll
    for (int r = 0; r < 8; ++r) {
      const int row = (r * 256 + tid) >> 3;
      const int kcs = asl ^ (row & 7);
      load_lds16(w1b + ((size_t)(blk * 256 + row)) * INF + k0 + kcs * 8,
                 (char*)Bs + (r * 256 + wid * 64) * 16);
    }
    __syncthreads();
#pragma unroll
    for (int ks = 0; ks < 2; ++ks) {
      bf16x8 a[4], b[8];
#pragma unroll
      for (int mi = 0; mi < 4; ++mi) {
        const int row = wr * 64 + mi * 16 + (lane & 15);
        const int kc = ks * 4 + (lane >> 4);
        a[mi] = *(const bf16x8*)((const char*)As + row * 128 + ((kc ^ (row & 7)) << 4));
      }
#pragma unroll
      for (int ni = 0; ni < 8; ++ni) {
        const int row = wc * 128 + ni * 16 + (lane & 15);
        const int kc = ks * 4 + (lane >> 4);
        b[ni] = *(const bf16x8*)((const char*)Bs + row * 128 + ((kc ^ (row & 7)) << 4));
      }
#pragma unroll
      for (int mi = 0; mi < 4; ++mi)
#pragma unroll
        for (int ni = 0; ni < 8; ++ni)
          acc[mi][ni] = __builtin_amdgcn_mfma_f32_16x16x32_bf16(a[mi], b[ni], acc[mi][ni], 0, 0, 0);
    }
  }
  // epilogue: bias + relu + bf16 store (pad rows stored too; never consumed)
#pragma unroll
  for (int ni = 0; ni < 8; ++ni) {
    const int n = wc * 128 + ni * 16 + (lane & 15);
    const float bias = b1[blk * 256 + n];
#pragma unroll
    for (int mi = 0; mi < 4; ++mi) {
      const int m0 = wr * 64 + mi * 16 + (lane >> 4) * 4;
#pragma unroll
      for (int i = 0; i < 4; ++i) {
        float v = acc[mi][ni][i] + bias;
        v = v > 0.f ? v : 0.f;
        hg[(size_t)(goff + m0 + i) * BLKSZ + n] = f2bf(v);
      }
    }
  }
}

// ---------------- fc2: out += h @ W2blk^T (atomic scatter) ----------------
__global__ __launch_bounds__(256, 2) void k_fc2(
    const unsigned short* __restrict__ hg, const unsigned short* __restrict__ w2b,
    const unsigned short* __restrict__ list, const unsigned* __restrict__ counts,
    const unsigned* __restrict__ off, float* __restrict__ out) {
  const int bid = blockIdx.x;
  const int blk = bid >> 7;
  const int tile = bid & 127;
  const unsigned cnt = counts[blk];
  if ((unsigned)(tile * 128) >= cnt) return;
  const unsigned goff = off[blk] + tile * 128;
  const int rem = (int)cnt - tile * 128;

  __shared__ __align__(16) unsigned short As[128 * 64];
  __shared__ __align__(16) unsigned short Bs[256 * 64];
  __shared__ unsigned toks[128];

  const int tid = threadIdx.x;
  const int lane = tid & 63;
  const int wid = tid >> 6;
  const int wr = wid >> 1, wc = wid & 1;
  const int asl = tid & 7;

  if (tid < 128) toks[tid] = list[goff + tid] & 0x3FFFu;

  for (int ns = 0; ns < 4; ++ns) {
    f32x4 acc[4][8] = {};
    for (int k0 = 0; k0 < 256; k0 += 64) {
      __syncthreads();
#pragma unroll
      for (int r = 0; r < 4; ++r) {
        const int row = (r * 256 + tid) >> 3;
        const int kcs = asl ^ (row & 7);
        load_lds16(hg + (size_t)(goff + row) * BLKSZ + k0 + kcs * 8,
                   (char*)As + (r * 256 + wid * 64) * 16);
      }
#pragma unroll
      for (int r = 0; r < 8; ++r) {
        const int row = (r * 256 + tid) >> 3;
        const int kcs = asl ^ (row & 7);
        load_lds16(w2b + (size_t)(ns * 256 + row) * OUTF + blk * 256 + k0 + kcs * 8,
                   (char*)Bs + (r * 256 + wid * 64) * 16);
      }
      __syncthreads();
#pragma unroll
      for (int ks = 0; ks < 2; ++ks) {
        bf16x8 a[4], b[8];
#pragma unroll
        for (int mi = 0; mi < 4; ++mi) {
          const int row = wr * 64 + mi * 16 + (lane & 15);
          const int kc = ks * 4 + (lane >> 4);
          a[mi] = *(const bf16x8*)((const char*)As + row * 128 + ((kc ^ (row & 7)) << 4));
        }
#pragma unroll
        for (int ni = 0; ni < 8; ++ni) {
          const int row = wc * 128 + ni * 16 + (lane & 15);
          const int kc = ks * 4 + (lane >> 4);
          b[ni] = *(const bf16x8*)((const char*)Bs + row * 128 + ((kc ^ (row & 7)) << 4));
        }
#pragma unroll
        for (int mi = 0; mi < 4; ++mi)
#pragma unroll
          for (int ni = 0; ni < 8; ++ni)
            acc[mi][ni] = __builtin_amdgcn_mfma_f32_16x16x32_bf16(a[mi], b[ni], acc[mi][ni], 0, 0, 0);
      }
    }
    // epilogue: atomic scatter into out
#pragma unroll
    for (int mi = 0; mi < 4; ++mi) {
#pragma unroll
      for (int i = 0; i < 4; ++i) {
        const int mrow = wr * 64 + mi * 16 + (lane >> 4) * 4 + i;
        if (mrow < rem) {
          const unsigned tok = toks[mrow];
          float* orow = out + (size_t)tok * INF + ns * 256 + wc * 128 + (lane & 15);
#pragma unroll
          for (int ni = 0; ni < 8; ++ni)
            __hip_atomic_fetch_add(orow + ni * 16, acc[mi][ni][i],
                                   __ATOMIC_RELAXED, __HIP_MEMORY_SCOPE_AGENT);
        }
      }
    }
  }
}

extern "C" void kernel_launch(void* const* d_in, const int* in_sizes, int n_in,
                              void* d_out, int out_size, void* d_ws, size_t ws_size,
                              hipStream_t stream) {
  const float* x  = (const float*)d_in[0];
  const float* rw = (const float*)d_in[1];
  const float* rb = (const float*)d_in[2];
  const float* w1 = (const float*)d_in[3];
  const float* b1 = (const float*)d_in[4];
  const float* w2 = (const float*)d_in[5];
  const float* b2 = (const float*)d_in[6];
  float* out = (float*)d_out;

  char* ws = (char*)d_ws;
  unsigned short* xb   = (unsigned short*)(ws);             // 33,554,432 B
  unsigned short* w1b  = (unsigned short*)(ws + 33554432);  //  8,388,608 B
  unsigned short* w2b  = (unsigned short*)(ws + 41943040);  //  8,388,608 B
  unsigned short* hg   = (unsigned short*)(ws + 50331648);  // 34,603,008 B
  unsigned* tokb       = (unsigned*)(ws + 84934656);        //     65,536 B
  unsigned short* list = (unsigned short*)(ws + 85000192);  //    135,168 B
  unsigned* counts     = (unsigned*)(ws + 85135360);
  unsigned* off        = (unsigned*)(ws + 85135424);
  unsigned* cursors    = (unsigned*)(ws + 85135552);

  k_zero<<<dim3(133), dim3(256), 0, stream>>>((unsigned*)list, counts);
  k_convert<<<dim3(2048), dim3(256), 0, stream>>>(x, w1, w2, xb, w1b, w2b);
  k_router<<<dim3(64), dim3(256), 0, stream>>>(x, rw, rb, tokb, counts);
  k_scan<<<dim3(1), dim3(64), 0, stream>>>(counts, off, cursors);
  k_build<<<dim3(64), dim3(256), 0, stream>>>(tokb, cursors, list);
  k_init_out<<<dim3(2048), dim3(256), 0, stream>>>(b2, out);
  k_fc1<<<dim3(2048), dim3(256), 0, stream>>>(xb, w1b, b1, list, counts, off, hg);
  k_fc2<<<dim3(2048), dim3(256), 0, stream>>>(hg, w2b, list, counts, off, out);
}

// Round 2
// 439.401 us; speedup vs baseline: 1.2136x; 1.2136x over previous
//
#include <hip/hip_runtime.h>
#include <hip/hip_bf16.h>

#define NTOK   16384
#define INF    1024
#define OUTF   4096
#define NBLK   16
#define BLKSZ  256
#define KTOP   4
#define PADROWS 67584  /* 65536 + 16*128 */

typedef short bf16x8 __attribute__((ext_vector_type(8)));
typedef float f32x4 __attribute__((ext_vector_type(4)));
typedef unsigned short u16x8 __attribute__((ext_vector_type(8)));

__device__ __forceinline__ unsigned short f2bf(float f) {
  unsigned u = __float_as_uint(f);
  u += 0x7FFFu + ((u >> 16) & 1u);
  return (unsigned short)(u >> 16);
}

__device__ __forceinline__ void load_lds16(const void* g, void* l) {
  __builtin_amdgcn_global_load_lds(
      (const __attribute__((address_space(1))) unsigned int*)g,
      (__attribute__((address_space(3))) unsigned int*)l, 16, 0, 0);
}

// ---------------- zero counts + list pad ----------------
__global__ void k_zero(unsigned* __restrict__ list32, unsigned* __restrict__ counts) {
  int i = blockIdx.x * 256 + threadIdx.x;
  if (i < 33792) list32[i] = 0;            // 67584 u16 entries
  else if (i < 33808) counts[i - 33792] = 0;
}

// ---------------- fp32->bf16 conversion of x, w1, w2 ----------------
__global__ __launch_bounds__(256) void k_convert(
    const float* __restrict__ x, const float* __restrict__ w1,
    const float* __restrict__ w2, unsigned short* __restrict__ xb,
    unsigned short* __restrict__ w1b, unsigned short* __restrict__ w2b) {
  const size_t stride = (size_t)gridDim.x * 256;
  for (size_t i = (size_t)blockIdx.x * 256 + threadIdx.x; i < 6291456; i += stride) {
    const float4* src; ushort4* dst; size_t idx;
    if (i < 4194304)      { src = (const float4*)x;  dst = (ushort4*)xb;  idx = i; }
    else if (i < 5242880) { src = (const float4*)w1; dst = (ushort4*)w1b; idx = i - 4194304; }
    else                  { src = (const float4*)w2; dst = (ushort4*)w2b; idx = i - 5242880; }
    float4 v = src[idx];
    ushort4 o;
    o.x = f2bf(v.x); o.y = f2bf(v.y); o.z = f2bf(v.z); o.w = f2bf(v.w);
    dst[idx] = o;
  }
}

// ---------------- router: logits (f64 accum), top-4, counts ----------------
__global__ __launch_bounds__(256) void k_router(
    const float* __restrict__ x, const float* __restrict__ rw,
    const float* __restrict__ rb, unsigned* __restrict__ tok_blocks,
    unsigned* __restrict__ counts) {
  __shared__ float4 rwl[4096];  // full router_w [16][1024] fp32 = 64KB
  const int tid = threadIdx.x;
  const float4* rw4 = (const float4*)rw;
  for (int i = tid; i < 4096; i += 256) rwl[i] = rw4[i];
  __syncthreads();

  const int n = blockIdx.x * 256 + tid;
  double p[16];
#pragma unroll
  for (int j = 0; j < 16; ++j) p[j] = (double)rb[j];
  const float4* xr = (const float4*)(x + (size_t)n * INF);
  for (int d4 = 0; d4 < 256; ++d4) {
    const float4 xv = xr[d4];
#pragma unroll
    for (int j = 0; j < 16; ++j) {
      const float4 wv = rwl[j * 256 + d4];
      p[j] = fma((double)xv.x, (double)wv.x, p[j]);
      p[j] = fma((double)xv.y, (double)wv.y, p[j]);
      p[j] = fma((double)xv.z, (double)wv.z, p[j]);
      p[j] = fma((double)xv.w, (double)wv.w, p[j]);
    }
  }
  // rank: # of j2 strictly better (ties -> lower index wins, matching lax.top_k)
  unsigned packed = 0;
#pragma unroll
  for (int j = 0; j < 16; ++j) {
    int r = 0;
#pragma unroll
    for (int j2 = 0; j2 < 16; ++j2)
      r += (int)((p[j2] > p[j]) | ((p[j2] == p[j]) & (j2 < j)));
    if (r < KTOP) packed |= (unsigned)j << (8 * r);
  }
  tok_blocks[n] = packed;

  const int lane = tid & 63;
  for (int b = 0; b < 16; ++b) {
    bool sel = ((packed & 15u) == (unsigned)b) | (((packed >> 8) & 15u) == (unsigned)b) |
               (((packed >> 16) & 15u) == (unsigned)b) | (((packed >> 24) & 15u) == (unsigned)b);
    unsigned long long m = __ballot(sel);
    if (m) {
      int leader = __ffsll((unsigned long long)m) - 1;
      if (lane == leader) atomicAdd(&counts[b], (unsigned)__popcll(m));
    }
  }
}

// ---------------- scan: padded offsets + cursors ----------------
__global__ void k_scan(const unsigned* __restrict__ counts, unsigned* __restrict__ off,
                       unsigned* __restrict__ cursors) {
  if (threadIdx.x == 0 && blockIdx.x == 0) {
    unsigned o = 0;
    for (int i = 0; i < 16; ++i) {
      off[i] = o; cursors[i] = o;
      o += (counts[i] + 127u) & ~127u;
    }
    off[16] = o;
  }
}

// ---------------- build per-block token lists ----------------
__global__ __launch_bounds__(256) void k_build(
    const unsigned* __restrict__ tok_blocks, unsigned* __restrict__ cursors,
    unsigned short* __restrict__ list) {
  const int n = blockIdx.x * 256 + threadIdx.x;
  const unsigned packed = tok_blocks[n];
  const int lane = threadIdx.x & 63;
  for (int b = 0; b < 16; ++b) {
    int r = -1;
#pragma unroll
    for (int q = 0; q < 4; ++q)
      if (((packed >> (8 * q)) & 15u) == (unsigned)b) r = q;
    unsigned long long m = __ballot(r >= 0);
    if (m) {
      int leader = __ffsll((unsigned long long)m) - 1;
      unsigned base = 0;
      if (lane == leader) base = atomicAdd(&cursors[b], (unsigned)__popcll(m));
      base = (unsigned)__shfl((int)base, leader);
      if (r >= 0) {
        unsigned pos = base + (unsigned)__popcll(m & ((1ull << lane) - 1ull));
        list[pos] = (unsigned short)(n | (r << 14));
      }
    }
  }
}

// ---------------- fc1: h = relu(Xg @ W1blk^T + b1) -> hg (bf16) ----------------
__global__ __launch_bounds__(256, 2) void k_fc1(
    const unsigned short* __restrict__ xb, const unsigned short* __restrict__ w1b,
    const float* __restrict__ b1, const unsigned short* __restrict__ list,
    const unsigned* __restrict__ counts, const unsigned* __restrict__ off,
    unsigned short* __restrict__ hg) {
  const int bid = blockIdx.x;
  const int blk = bid >> 7;
  const int tile = bid & 127;
  const unsigned cnt = counts[blk];
  if ((unsigned)(tile * 128) >= cnt) return;
  const unsigned goff = off[blk] + tile * 128;

  __shared__ __align__(16) unsigned short As[128 * 64];
  __shared__ __align__(16) unsigned short Bs[256 * 64];
  __shared__ unsigned toks[128];

  const int tid = threadIdx.x;
  const int lane = tid & 63;
  const int wid = tid >> 6;
  const int wr = wid >> 1, wc = wid & 1;

  if (tid < 128) toks[tid] = list[goff + tid] & 0x3FFFu;
  __syncthreads();

  unsigned tokr[4]; int arow[4];
#pragma unroll
  for (int r = 0; r < 4; ++r) { arow[r] = (r * 256 + tid) >> 3; tokr[r] = toks[arow[r]]; }
  const int asl = tid & 7;

  f32x4 acc[4][8] = {};

  for (int k0 = 0; k0 < 1024; k0 += 64) {
    __syncthreads();
#pragma unroll
    for (int r = 0; r < 4; ++r) {
      const int kcs = asl ^ (arow[r] & 7);
      load_lds16(xb + (size_t)tokr[r] * INF + k0 + kcs * 8,
                 (char*)As + (r * 256 + wid * 64) * 16);
    }
#pragma unroll
    for (int r = 0; r < 8; ++r) {
      const int row = (r * 256 + tid) >> 3;
      const int kcs = asl ^ (row & 7);
      load_lds16(w1b + ((size_t)(blk * 256 + row)) * INF + k0 + kcs * 8,
                 (char*)Bs + (r * 256 + wid * 64) * 16);
    }
    __syncthreads();
#pragma unroll
    for (int ks = 0; ks < 2; ++ks) {
      bf16x8 a[4], b[8];
#pragma unroll
      for (int mi = 0; mi < 4; ++mi) {
        const int row = wr * 64 + mi * 16 + (lane & 15);
        const int kc = ks * 4 + (lane >> 4);
        a[mi] = *(const bf16x8*)((const char*)As + row * 128 + ((kc ^ (row & 7)) << 4));
      }
#pragma unroll
      for (int ni = 0; ni < 8; ++ni) {
        const int row = wc * 128 + ni * 16 + (lane & 15);
        const int kc = ks * 4 + (lane >> 4);
        b[ni] = *(const bf16x8*)((const char*)Bs + row * 128 + ((kc ^ (row & 7)) << 4));
      }
#pragma unroll
      for (int mi = 0; mi < 4; ++mi)
#pragma unroll
        for (int ni = 0; ni < 8; ++ni)
          acc[mi][ni] = __builtin_amdgcn_mfma_f32_16x16x32_bf16(a[mi], b[ni], acc[mi][ni], 0, 0, 0);
    }
  }
  // epilogue: bias + relu + bf16 store (pad rows stored too; never consumed)
#pragma unroll
  for (int ni = 0; ni < 8; ++ni) {
    const int n = wc * 128 + ni * 16 + (lane & 15);
    const float bias = b1[blk * 256 + n];
#pragma unroll
    for (int mi = 0; mi < 4; ++mi) {
      const int m0 = wr * 64 + mi * 16 + (lane >> 4) * 4;
#pragma unroll
      for (int i = 0; i < 4; ++i) {
        float v = acc[mi][ni][i] + bias;
        v = v > 0.f ? v : 0.f;
        hg[(size_t)(goff + m0 + i) * BLKSZ + n] = f2bf(v);
      }
    }
  }
}

// ---------------- fc2: part[tok*4+r] = h @ W2blk^T (bf16, no atomics) ----------------
__global__ __launch_bounds__(256, 2) void k_fc2(
    const unsigned short* __restrict__ hg, const unsigned short* __restrict__ w2b,
    const unsigned short* __restrict__ list, const unsigned* __restrict__ counts,
    const unsigned* __restrict__ off, unsigned short* __restrict__ part) {
  const int bid = blockIdx.x;
  const int blk = bid >> 7;
  const int tile = bid & 127;
  const unsigned cnt = counts[blk];
  if ((unsigned)(tile * 128) >= cnt) return;
  const unsigned goff = off[blk] + tile * 128;
  const int rem = (int)cnt - tile * 128;

  __shared__ __align__(16) unsigned short As[128 * 64];
  __shared__ __align__(16) unsigned short Bs[256 * 64];
  __shared__ unsigned toks[128];

  const int tid = threadIdx.x;
  const int lane = tid & 63;
  const int wid = tid >> 6;
  const int wr = wid >> 1, wc = wid & 1;
  const int asl = tid & 7;

  if (tid < 128) toks[tid] = list[goff + tid];  // keep slot bits

  for (int ns = 0; ns < 4; ++ns) {
    f32x4 acc[4][8] = {};
    for (int k0 = 0; k0 < 256; k0 += 64) {
      __syncthreads();
#pragma unroll
      for (int r = 0; r < 4; ++r) {
        const int row = (r * 256 + tid) >> 3;
        const int kcs = asl ^ (row & 7);
        load_lds16(hg + (size_t)(goff + row) * BLKSZ + k0 + kcs * 8,
                   (char*)As + (r * 256 + wid * 64) * 16);
      }
#pragma unroll
      for (int r = 0; r < 8; ++r) {
        const int row = (r * 256 + tid) >> 3;
        const int kcs = asl ^ (row & 7);
        load_lds16(w2b + (size_t)(ns * 256 + row) * OUTF + blk * 256 + k0 + kcs * 8,
                   (char*)Bs + (r * 256 + wid * 64) * 16);
      }
      __syncthreads();
#pragma unroll
      for (int ks = 0; ks < 2; ++ks) {
        bf16x8 a[4], b[8];
#pragma unroll
        for (int mi = 0; mi < 4; ++mi) {
          const int row = wr * 64 + mi * 16 + (lane & 15);
          const int kc = ks * 4 + (lane >> 4);
          a[mi] = *(const bf16x8*)((const char*)As + row * 128 + ((kc ^ (row & 7)) << 4));
        }
#pragma unroll
        for (int ni = 0; ni < 8; ++ni) {
          const int row = wc * 128 + ni * 16 + (lane & 15);
          const int kc = ks * 4 + (lane >> 4);
          b[ni] = *(const bf16x8*)((const char*)Bs + row * 128 + ((kc ^ (row & 7)) << 4));
        }
#pragma unroll
        for (int mi = 0; mi < 4; ++mi)
#pragma unroll
          for (int ni = 0; ni < 8; ++ni)
            acc[mi][ni] = __builtin_amdgcn_mfma_f32_16x16x32_bf16(a[mi], b[ni], acc[mi][ni], 0, 0, 0);
      }
    }
    // epilogue: bf16 partial store, row (tok*4 + slot)
#pragma unroll
    for (int mi = 0; mi < 4; ++mi) {
#pragma unroll
      for (int i = 0; i < 4; ++i) {
        const int mrow = wr * 64 + mi * 16 + (lane >> 4) * 4 + i;
        if (mrow < rem) {
          const unsigned e = toks[mrow];
          const unsigned tok = e & 0x3FFFu;
          const unsigned slot = e >> 14;
          unsigned short* prow = part + ((size_t)tok * 4 + slot) * 1024 +
                                 ns * 256 + wc * 128 + (lane & 15);
#pragma unroll
          for (int ni = 0; ni < 8; ++ni)
            prow[ni * 16] = f2bf(acc[mi][ni][i]);
        }
      }
    }
  }
}

// ---------------- reduce: out = b2 + sum_r part[tok*4+r] ----------------
__global__ __launch_bounds__(256) void k_reduce(const unsigned short* __restrict__ part,
                                                const float* __restrict__ b2,
                                                float* __restrict__ out) {
  const size_t idx = (size_t)blockIdx.x * 256 + threadIdx.x;  // 0..2097151
  const int tok = (int)(idx >> 7);
  const int c8 = (int)(idx & 127) << 3;
  const unsigned short* p = part + (size_t)tok * 4096 + c8;
  const float4* b24 = (const float4*)(b2 + c8);
  float4 bl = b24[0], bh = b24[1];
  float s[8] = {bl.x, bl.y, bl.z, bl.w, bh.x, bh.y, bh.z, bh.w};
#pragma unroll
  for (int r = 0; r < 4; ++r) {
    u16x8 v = *(const u16x8*)(p + r * 1024);
#pragma unroll
    for (int j = 0; j < 8; ++j)
      s[j] += __uint_as_float((unsigned)(unsigned short)v[j] << 16);
  }
  float4* o = (float4*)(out + (size_t)tok * 1024 + c8);
  o[0] = make_float4(s[0], s[1], s[2], s[3]);
  o[1] = make_float4(s[4], s[5], s[6], s[7]);
}

extern "C" void kernel_launch(void* const* d_in, const int* in_sizes, int n_in,
                              void* d_out, int out_size, void* d_ws, size_t ws_size,
                              hipStream_t stream) {
  const float* x  = (const float*)d_in[0];
  const float* rw = (const float*)d_in[1];
  const float* rb = (const float*)d_in[2];
  const float* w1 = (const float*)d_in[3];
  const float* b1 = (const float*)d_in[4];
  const float* w2 = (const float*)d_in[5];
  const float* b2 = (const float*)d_in[6];
  float* out = (float*)d_out;

  char* ws = (char*)d_ws;
  unsigned short* xb   = (unsigned short*)(ws);              // 33,554,432 B
  unsigned short* w1b  = (unsigned short*)(ws + 33554432);   //  8,388,608 B
  unsigned short* w2b  = (unsigned short*)(ws + 41943040);   //  8,388,608 B
  unsigned short* hg   = (unsigned short*)(ws + 50331648);   // 34,603,008 B
  unsigned short* part = (unsigned short*)(ws + 84934656);   // 134,217,728 B
  unsigned* tokb       = (unsigned*)(ws + 219152384);        //     65,536 B
  unsigned short* list = (unsigned short*)(ws + 219217920);  //    135,168 B
  unsigned* counts     = (unsigned*)(ws + 219353088);
  unsigned* off        = (unsigned*)(ws + 219353216);
  unsigned* cursors    = (unsigned*)(ws + 219353344);

  k_zero<<<dim3(133), dim3(256), 0, stream>>>((unsigned*)list, counts);
  k_convert<<<dim3(2048), dim3(256), 0, stream>>>(x, w1, w2, xb, w1b, w2b);
  k_router<<<dim3(64), dim3(256), 0, stream>>>(x, rw, rb, tokb, counts);
  k_scan<<<dim3(1), dim3(64), 0, stream>>>(counts, off, cursors);
  k_build<<<dim3(64), dim3(256), 0, stream>>>(tokb, cursors, list);
  k_fc1<<<dim3(2048), dim3(256), 0, stream>>>(xb, w1b, b1, list, counts, off, hg);
  k_fc2<<<dim3(2048), dim3(256), 0, stream>>>(hg, w2b, list, counts, off, part);
  k_reduce<<<dim3(8192), dim3(256), 0, stream>>>(part, b2, out);
}

// Round 3
// 332.651 us; speedup vs baseline: 1.6030x; 1.3209x over previous
//
#include <hip/hip_runtime.h>
#include <hip/hip_bf16.h>

#define NTOK   16384
#define INF    1024
#define OUTF   4096
#define NBLK   16
#define BLKSZ  256
#define KTOP   4
#define PADROWS 67584  /* 65536 + 16*128 */

typedef short bf16x8 __attribute__((ext_vector_type(8)));
typedef float f32x4 __attribute__((ext_vector_type(4)));
typedef unsigned short u16x8 __attribute__((ext_vector_type(8)));

__device__ __forceinline__ unsigned short f2bf(float f) {
  unsigned u = __float_as_uint(f);
  u += 0x7FFFu + ((u >> 16) & 1u);
  return (unsigned short)(u >> 16);
}

__device__ __forceinline__ void load_lds16(const void* g, void* l) {
  __builtin_amdgcn_global_load_lds(
      (const __attribute__((address_space(1))) unsigned int*)g,
      (__attribute__((address_space(3))) unsigned int*)l, 16, 0, 0);
}

__device__ __forceinline__ double shfl_xor_d(double v, int m) {
  long long l = __double_as_longlong(v);
  int lo = (int)(l & 0xFFFFFFFFll), hi = (int)(l >> 32);
  lo = __shfl_xor(lo, m);
  hi = __shfl_xor(hi, m);
  return __longlong_as_double(((long long)hi << 32) | (unsigned long long)(unsigned)lo);
}

// ---------------- zero counts + list pad ----------------
__global__ void k_zero(unsigned* __restrict__ list32, unsigned* __restrict__ counts) {
  int i = blockIdx.x * 256 + threadIdx.x;
  if (i < 33792) list32[i] = 0;            // 67584 u16 entries
  else if (i < 33808) counts[i - 33792] = 0;
}

// ---------------- fp32->bf16 conversion of w1, w2 ----------------
__global__ __launch_bounds__(256) void k_convert(
    const float* __restrict__ w1, const float* __restrict__ w2,
    unsigned short* __restrict__ w1b, unsigned short* __restrict__ w2b) {
  const size_t stride = (size_t)gridDim.x * 256;
  for (size_t i = (size_t)blockIdx.x * 256 + threadIdx.x; i < 2097152; i += stride) {
    const float4* src; ushort4* dst; size_t idx;
    if (i < 1048576) { src = (const float4*)w1; dst = (ushort4*)w1b; idx = i; }
    else             { src = (const float4*)w2; dst = (ushort4*)w2b; idx = i - 1048576; }
    float4 v = src[idx];
    ushort4 o;
    o.x = f2bf(v.x); o.y = f2bf(v.y); o.z = f2bf(v.z); o.w = f2bf(v.w);
    dst[idx] = o;
  }
}

// ---------------- router: logits (f64, 8 lanes/token), top-4, counts, x->bf16 ----------------
__global__ __launch_bounds__(256) void k_router(
    const float* __restrict__ x, const float* __restrict__ rw,
    const float* __restrict__ rb, unsigned* __restrict__ tok_blocks,
    unsigned* __restrict__ counts, unsigned short* __restrict__ xb) {
  __shared__ float4 rwl[4096];  // full router_w [16][1024] fp32 = 64KB (reused as hist after)
  const int tid = threadIdx.x;
  const float4* rw4 = (const float4*)rw;
  for (int i = tid; i < 4096; i += 256) rwl[i] = rw4[i];
  __syncthreads();

  const int n = blockIdx.x * 32 + (tid >> 3);
  const int q = tid & 7;
  double p[16];
#pragma unroll
  for (int j = 0; j < 16; ++j) p[j] = 0.0;
  const float4* xr = (const float4*)(x + (size_t)n * INF);
  ushort4* xbr = (ushort4*)(xb + (size_t)n * INF);
#pragma unroll 4
  for (int i = 0; i < 32; ++i) {
    const int d4 = q + i * 8;
    const float4 xv = xr[d4];
    ushort4 o;
    o.x = f2bf(xv.x); o.y = f2bf(xv.y); o.z = f2bf(xv.z); o.w = f2bf(xv.w);
    xbr[d4] = o;
#pragma unroll
    for (int j = 0; j < 16; ++j) {
      const float4 wv = rwl[j * 256 + d4];
      p[j] = fma((double)xv.x, (double)wv.x, p[j]);
      p[j] = fma((double)xv.y, (double)wv.y, p[j]);
      p[j] = fma((double)xv.z, (double)wv.z, p[j]);
      p[j] = fma((double)xv.w, (double)wv.w, p[j]);
    }
  }
  // reduce across the 8 lanes of this token
#pragma unroll
  for (int j = 0; j < 16; ++j) {
    double v = p[j];
    v += shfl_xor_d(v, 1);
    v += shfl_xor_d(v, 2);
    v += shfl_xor_d(v, 4);
    p[j] = v + (double)rb[j];
  }

  __syncthreads();
  unsigned* hist = (unsigned*)rwl;
  if (tid < 16) hist[tid] = 0;
  __syncthreads();

  if (q == 0) {
    // rank: # of j2 strictly better (ties -> lower index wins, matching lax.top_k)
    unsigned packed = 0;
#pragma unroll
    for (int j = 0; j < 16; ++j) {
      int r = 0;
#pragma unroll
      for (int j2 = 0; j2 < 16; ++j2)
        r += (int)((p[j2] > p[j]) | ((p[j2] == p[j]) & (j2 < j)));
      if (r < KTOP) packed |= (unsigned)j << (8 * r);
    }
    tok_blocks[n] = packed;
    atomicAdd(&hist[packed & 15u], 1u);
    atomicAdd(&hist[(packed >> 8) & 15u], 1u);
    atomicAdd(&hist[(packed >> 16) & 15u], 1u);
    atomicAdd(&hist[(packed >> 24) & 15u], 1u);
  }
  __syncthreads();
  if (tid < 16 && hist[tid]) atomicAdd(&counts[tid], hist[tid]);
}

// ---------------- scan: padded offsets + cursors ----------------
__global__ void k_scan(const unsigned* __restrict__ counts, unsigned* __restrict__ off,
                       unsigned* __restrict__ cursors) {
  if (threadIdx.x == 0 && blockIdx.x == 0) {
    unsigned o = 0;
    for (int i = 0; i < 16; ++i) {
      off[i] = o; cursors[i] = o;
      o += (counts[i] + 127u) & ~127u;
    }
    off[16] = o;
  }
}

// ---------------- build per-block token lists ----------------
__global__ __launch_bounds__(256) void k_build(
    const unsigned* __restrict__ tok_blocks, unsigned* __restrict__ cursors,
    unsigned short* __restrict__ list) {
  const int n = blockIdx.x * 256 + threadIdx.x;
  const unsigned packed = tok_blocks[n];
  const int lane = threadIdx.x & 63;
  for (int b = 0; b < 16; ++b) {
    int r = -1;
#pragma unroll
    for (int q = 0; q < 4; ++q)
      if (((packed >> (8 * q)) & 15u) == (unsigned)b) r = q;
    unsigned long long m = __ballot(r >= 0);
    if (m) {
      int leader = __ffsll((unsigned long long)m) - 1;
      unsigned base = 0;
      if (lane == leader) base = atomicAdd(&cursors[b], (unsigned)__popcll(m));
      base = (unsigned)__shfl((int)base, leader);
      if (r >= 0) {
        unsigned pos = base + (unsigned)__popcll(m & ((1ull << lane) - 1ull));
        list[pos] = (unsigned short)(n | (r << 14));
      }
    }
  }
}

// ---------------- fc1: h = relu(Xg @ W1blk^T + b1) -> hg (bf16) ----------------
__global__ __launch_bounds__(256, 2) void k_fc1(
    const unsigned short* __restrict__ xb, const unsigned short* __restrict__ w1b,
    const float* __restrict__ b1, const unsigned short* __restrict__ list,
    const unsigned* __restrict__ counts, const unsigned* __restrict__ off,
    unsigned short* __restrict__ hg) {
  const int bid = blockIdx.x;
  const int blk = bid >> 7;
  const int tile = bid & 127;
  const unsigned cnt = counts[blk];
  if ((unsigned)(tile * 128) >= cnt) return;
  const unsigned goff = off[blk] + tile * 128;

  __shared__ __align__(16) unsigned short As[128 * 64];
  __shared__ __align__(16) unsigned short Bs[256 * 64];
  __shared__ unsigned toks[128];

  const int tid = threadIdx.x;
  const int lane = tid & 63;
  const int wid = tid >> 6;
  const int wr = wid >> 1, wc = wid & 1;

  if (tid < 128) toks[tid] = list[goff + tid] & 0x3FFFu;
  __syncthreads();

  unsigned tokr[4]; int arow[4];
#pragma unroll
  for (int r = 0; r < 4; ++r) { arow[r] = (r * 256 + tid) >> 3; tokr[r] = toks[arow[r]]; }
  const int asl = tid & 7;

  f32x4 acc[4][8] = {};

  for (int k0 = 0; k0 < 1024; k0 += 64) {
    __syncthreads();
#pragma unroll
    for (int r = 0; r < 4; ++r) {
      const int kcs = asl ^ (arow[r] & 7);
      load_lds16(xb + (size_t)tokr[r] * INF + k0 + kcs * 8,
                 (char*)As + (r * 256 + wid * 64) * 16);
    }
#pragma unroll
    for (int r = 0; r < 8; ++r) {
      const int row = (r * 256 + tid) >> 3;
      const int kcs = asl ^ (row & 7);
      load_lds16(w1b + ((size_t)(blk * 256 + row)) * INF + k0 + kcs * 8,
                 (char*)Bs + (r * 256 + wid * 64) * 16);
    }
    __syncthreads();
#pragma unroll
    for (int ks = 0; ks < 2; ++ks) {
      bf16x8 a[4], b[8];
#pragma unroll
      for (int mi = 0; mi < 4; ++mi) {
        const int row = wr * 64 + mi * 16 + (lane & 15);
        const int kc = ks * 4 + (lane >> 4);
        a[mi] = *(const bf16x8*)((const char*)As + row * 128 + ((kc ^ (row & 7)) << 4));
      }
#pragma unroll
      for (int ni = 0; ni < 8; ++ni) {
        const int row = wc * 128 + ni * 16 + (lane & 15);
        const int kc = ks * 4 + (lane >> 4);
        b[ni] = *(const bf16x8*)((const char*)Bs + row * 128 + ((kc ^ (row & 7)) << 4));
      }
#pragma unroll
      for (int mi = 0; mi < 4; ++mi)
#pragma unroll
        for (int ni = 0; ni < 8; ++ni)
          acc[mi][ni] = __builtin_amdgcn_mfma_f32_16x16x32_bf16(a[mi], b[ni], acc[mi][ni], 0, 0, 0);
    }
  }
  // epilogue: bias + relu + bf16 store (pad rows stored too; never consumed)
#pragma unroll
  for (int ni = 0; ni < 8; ++ni) {
    const int n = wc * 128 + ni * 16 + (lane & 15);
    const float bias = b1[blk * 256 + n];
#pragma unroll
    for (int mi = 0; mi < 4; ++mi) {
      const int m0 = wr * 64 + mi * 16 + (lane >> 4) * 4;
#pragma unroll
      for (int i = 0; i < 4; ++i) {
        float v = acc[mi][ni][i] + bias;
        v = v > 0.f ? v : 0.f;
        hg[(size_t)(goff + m0 + i) * BLKSZ + n] = f2bf(v);
      }
    }
  }
}

// ---------------- fc2: part[tok*4+r] = h @ W2blk^T (bf16, no atomics) ----------------
__global__ __launch_bounds__(256, 2) void k_fc2(
    const unsigned short* __restrict__ hg, const unsigned short* __restrict__ w2b,
    const unsigned short* __restrict__ list, const unsigned* __restrict__ counts,
    const unsigned* __restrict__ off, unsigned short* __restrict__ part) {
  const int bid = blockIdx.x;
  const int blk = bid >> 7;
  const int tile = bid & 127;
  const unsigned cnt = counts[blk];
  if ((unsigned)(tile * 128) >= cnt) return;
  const unsigned goff = off[blk] + tile * 128;
  const int rem = (int)cnt - tile * 128;

  __shared__ __align__(16) unsigned short As[128 * 64];
  __shared__ __align__(16) unsigned short Bs[256 * 64];
  __shared__ unsigned toks[128];

  const int tid = threadIdx.x;
  const int lane = tid & 63;
  const int wid = tid >> 6;
  const int wr = wid >> 1, wc = wid & 1;
  const int asl = tid & 7;

  if (tid < 128) toks[tid] = list[goff + tid];  // keep slot bits

  for (int ns = 0; ns < 4; ++ns) {
    f32x4 acc[4][8] = {};
    for (int k0 = 0; k0 < 256; k0 += 64) {
      __syncthreads();
#pragma unroll
      for (int r = 0; r < 4; ++r) {
        const int row = (r * 256 + tid) >> 3;
        const int kcs = asl ^ (row & 7);
        load_lds16(hg + (size_t)(goff + row) * BLKSZ + k0 + kcs * 8,
                   (char*)As + (r * 256 + wid * 64) * 16);
      }
#pragma unroll
      for (int r = 0; r < 8; ++r) {
        const int row = (r * 256 + tid) >> 3;
        const int kcs = asl ^ (row & 7);
        load_lds16(w2b + (size_t)(ns * 256 + row) * OUTF + blk * 256 + k0 + kcs * 8,
                   (char*)Bs + (r * 256 + wid * 64) * 16);
      }
      __syncthreads();
#pragma unroll
      for (int ks = 0; ks < 2; ++ks) {
        bf16x8 a[4], b[8];
#pragma unroll
        for (int mi = 0; mi < 4; ++mi) {
          const int row = wr * 64 + mi * 16 + (lane & 15);
          const int kc = ks * 4 + (lane >> 4);
          a[mi] = *(const bf16x8*)((const char*)As + row * 128 + ((kc ^ (row & 7)) << 4));
        }
#pragma unroll
        for (int ni = 0; ni < 8; ++ni) {
          const int row = wc * 128 + ni * 16 + (lane & 15);
          const int kc = ks * 4 + (lane >> 4);
          b[ni] = *(const bf16x8*)((const char*)Bs + row * 128 + ((kc ^ (row & 7)) << 4));
        }
#pragma unroll
        for (int mi = 0; mi < 4; ++mi)
#pragma unroll
          for (int ni = 0; ni < 8; ++ni)
            acc[mi][ni] = __builtin_amdgcn_mfma_f32_16x16x32_bf16(a[mi], b[ni], acc[mi][ni], 0, 0, 0);
      }
    }
    // epilogue: bf16 partial store, row (tok*4 + slot)
#pragma unroll
    for (int mi = 0; mi < 4; ++mi) {
#pragma unroll
      for (int i = 0; i < 4; ++i) {
        const int mrow = wr * 64 + mi * 16 + (lane >> 4) * 4 + i;
        if (mrow < rem) {
          const unsigned e = toks[mrow];
          const unsigned tok = e & 0x3FFFu;
          const unsigned slot = e >> 14;
          unsigned short* prow = part + ((size_t)tok * 4 + slot) * 1024 +
                                 ns * 256 + wc * 128 + (lane & 15);
#pragma unroll
          for (int ni = 0; ni < 8; ++ni)
            prow[ni * 16] = f2bf(acc[mi][ni][i]);
        }
      }
    }
  }
}

// ---------------- reduce: out = b2 + sum_r part[tok*4+r] ----------------
__global__ __launch_bounds__(256) void k_reduce(const unsigned short* __restrict__ part,
                                                const float* __restrict__ b2,
                                                float* __restrict__ out) {
  const size_t idx = (size_t)blockIdx.x * 256 + threadIdx.x;  // 0..2097151
  const int tok = (int)(idx >> 7);
  const int c8 = (int)(idx & 127) << 3;
  const unsigned short* p = part + (size_t)tok * 4096 + c8;
  const float4* b24 = (const float4*)(b2 + c8);
  float4 bl = b24[0], bh = b24[1];
  float s[8] = {bl.x, bl.y, bl.z, bl.w, bh.x, bh.y, bh.z, bh.w};
#pragma unroll
  for (int r = 0; r < 4; ++r) {
    u16x8 v = *(const u16x8*)(p + r * 1024);
#pragma unroll
    for (int j = 0; j < 8; ++j)
      s[j] += __uint_as_float((unsigned)(unsigned short)v[j] << 16);
  }
  float4* o = (float4*)(out + (size_t)tok * 1024 + c8);
  o[0] = make_float4(s[0], s[1], s[2], s[3]);
  o[1] = make_float4(s[4], s[5], s[6], s[7]);
}

extern "C" void kernel_launch(void* const* d_in, const int* in_sizes, int n_in,
                              void* d_out, int out_size, void* d_ws, size_t ws_size,
                              hipStream_t stream) {
  const float* x  = (const float*)d_in[0];
  const float* rw = (const float*)d_in[1];
  const float* rb = (const float*)d_in[2];
  const float* w1 = (const float*)d_in[3];
  const float* b1 = (const float*)d_in[4];
  const float* w2 = (const float*)d_in[5];
  const float* b2 = (const float*)d_in[6];
  float* out = (float*)d_out;

  char* ws = (char*)d_ws;
  unsigned short* xb   = (unsigned short*)(ws);              // 33,554,432 B
  unsigned short* w1b  = (unsigned short*)(ws + 33554432);   //  8,388,608 B
  unsigned short* w2b  = (unsigned short*)(ws + 41943040);   //  8,388,608 B
  unsigned short* hg   = (unsigned short*)(ws + 50331648);   // 34,603,008 B
  unsigned short* part = (unsigned short*)(ws + 84934656);   // 134,217,728 B
  unsigned* tokb       = (unsigned*)(ws + 219152384);        //     65,536 B
  unsigned short* list = (unsigned short*)(ws + 219217920);  //    135,168 B
  unsigned* counts     = (unsigned*)(ws + 219353088);
  unsigned* off        = (unsigned*)(ws + 219353216);
  unsigned* cursors    = (unsigned*)(ws + 219353344);

  k_zero<<<dim3(133), dim3(256), 0, stream>>>((unsigned*)list, counts);
  k_convert<<<dim3(1024), dim3(256), 0, stream>>>(w1, w2, w1b, w2b);
  k_router<<<dim3(512), dim3(256), 0, stream>>>(x, rw, rb, tokb, counts, xb);
  k_scan<<<dim3(1), dim3(64), 0, stream>>>(counts, off, cursors);
  k_build<<<dim3(64), dim3(256), 0, stream>>>(tokb, cursors, list);
  k_fc1<<<dim3(2048), dim3(256), 0, stream>>>(xb, w1b, b1, list, counts, off, hg);
  k_fc2<<<dim3(2048), dim3(256), 0, stream>>>(hg, w2b, list, counts, off, part);
  k_reduce<<<dim3(8192), dim3(256), 0, stream>>>(part, b2, out);
}

// Round 4
// 316.538 us; speedup vs baseline: 1.6846x; 1.0509x over previous
//
#include <hip/hip_runtime.h>
#include <hip/hip_bf16.h>

#define NTOK   16384
#define INF    1024
#define OUTF   4096
#define NBLK   16
#define BLKSZ  256
#define KTOP   4

typedef short bf16x8 __attribute__((ext_vector_type(8)));
typedef float f32x4 __attribute__((ext_vector_type(4)));
typedef unsigned short u16x8 __attribute__((ext_vector_type(8)));

__device__ __forceinline__ unsigned short f2bf(float f) {
  unsigned u = __float_as_uint(f);
  u += 0x7FFFu + ((u >> 16) & 1u);
  return (unsigned short)(u >> 16);
}

__device__ __forceinline__ void load_lds16(const void* g, void* l) {
  __builtin_amdgcn_global_load_lds(
      (const __attribute__((address_space(1))) unsigned int*)g,
      (__attribute__((address_space(3))) unsigned int*)l, 16, 0, 0);
}

__device__ __forceinline__ double shfl_xor_d(double v, int m) {
  long long l = __double_as_longlong(v);
  int lo = (int)(l & 0xFFFFFFFFll), hi = (int)(l >> 32);
  lo = __shfl_xor(lo, m);
  hi = __shfl_xor(hi, m);
  return __longlong_as_double(((long long)hi << 32) | (unsigned long long)(unsigned)lo);
}

// pi(j): storage j = 128*wc + 8*c16 + ni  <->  original col = 128*wc + 16*ni + c16
__device__ __forceinline__ int pi_perm(int j) {
  return (j & 128) | ((j & 7) << 4) | ((j >> 3) & 15);
}

// ---------------- zero counts + list pad ----------------
__global__ void k_zero(unsigned* __restrict__ list32, unsigned* __restrict__ counts) {
  int i = blockIdx.x * 256 + threadIdx.x;
  if (i < 33792) list32[i] = 0;            // 67584 u16 entries
  else if (i < 33808) counts[i - 33792] = 0;
}

// ---------------- convert: w1->bf16 linear, w2->bf16 pi-permuted, b1p f32 permuted ----------------
__global__ __launch_bounds__(256) void k_convert(
    const float* __restrict__ w1, const float* __restrict__ w2,
    const float* __restrict__ b1, unsigned short* __restrict__ w1b,
    unsigned short* __restrict__ w2p, float* __restrict__ b1p) {
  const size_t stride = (size_t)gridDim.x * 256;
  for (size_t i = (size_t)blockIdx.x * 256 + threadIdx.x; i < 1573376; i += stride) {
    if (i < 1048576) {
      float4 v = ((const float4*)w1)[i];
      ushort4 o;
      o.x = f2bf(v.x); o.y = f2bf(v.y); o.z = f2bf(v.z); o.w = f2bf(v.w);
      ((ushort4*)w1b)[i] = o;
    } else if (i < 1572864) {
      const size_t g = i - 1048576;          // u16x8 group of w2p
      const int d = (int)(g >> 9);           // 512 groups per 4096-row
      const int rest = (int)(g & 511);
      const int jg = rest * 8;               // col group start in [0,4096)
      const int blk = jg >> 8;
      const int j0 = jg & 255;
      const float* src = w2 + (size_t)d * 4096 + blk * 256;
      u16x8 o;
#pragma unroll
      for (int ni = 0; ni < 8; ++ni) o[ni] = f2bf(src[pi_perm(j0 + ni)]);
      *(u16x8*)(w2p + (size_t)d * 4096 + jg) = o;
    } else {
      const int idx = (int)(i - 1572864);    // 512 groups of 8 for b1p
      const int jg = idx * 8;
      const int blk = jg >> 8;
      const int j0 = jg & 255;
      const float* src = b1 + blk * 256;
      float o[8];
#pragma unroll
      for (int ni = 0; ni < 8; ++ni) o[ni] = src[pi_perm(j0 + ni)];
      float4* dst = (float4*)(b1p + jg);
      dst[0] = make_float4(o[0], o[1], o[2], o[3]);
      dst[1] = make_float4(o[4], o[5], o[6], o[7]);
    }
  }
}

// ---------------- router: logits (f64, 8 lanes/token), top-4, counts, x->bf16 ----------------
__global__ __launch_bounds__(256) void k_router(
    const float* __restrict__ x, const float* __restrict__ rw,
    const float* __restrict__ rb, unsigned* __restrict__ tok_blocks,
    unsigned* __restrict__ counts, unsigned short* __restrict__ xb) {
  __shared__ float4 rwl[4096];  // full router_w [16][1024] fp32 = 64KB (reused as hist after)
  const int tid = threadIdx.x;
  const float4* rw4 = (const float4*)rw;
  for (int i = tid; i < 4096; i += 256) rwl[i] = rw4[i];
  __syncthreads();

  const int n = blockIdx.x * 32 + (tid >> 3);
  const int q = tid & 7;
  double p[16];
#pragma unroll
  for (int j = 0; j < 16; ++j) p[j] = 0.0;
  const float4* xr = (const float4*)(x + (size_t)n * INF);
  ushort4* xbr = (ushort4*)(xb + (size_t)n * INF);
#pragma unroll 4
  for (int i = 0; i < 32; ++i) {
    const int d4 = q + i * 8;
    const float4 xv = xr[d4];
    ushort4 o;
    o.x = f2bf(xv.x); o.y = f2bf(xv.y); o.z = f2bf(xv.z); o.w = f2bf(xv.w);
    xbr[d4] = o;
#pragma unroll
    for (int j = 0; j < 16; ++j) {
      const float4 wv = rwl[j * 256 + d4];
      p[j] = fma((double)xv.x, (double)wv.x, p[j]);
      p[j] = fma((double)xv.y, (double)wv.y, p[j]);
      p[j] = fma((double)xv.z, (double)wv.z, p[j]);
      p[j] = fma((double)xv.w, (double)wv.w, p[j]);
    }
  }
#pragma unroll
  for (int j = 0; j < 16; ++j) {
    double v = p[j];
    v += shfl_xor_d(v, 1);
    v += shfl_xor_d(v, 2);
    v += shfl_xor_d(v, 4);
    p[j] = v + (double)rb[j];
  }

  __syncthreads();
  unsigned* hist = (unsigned*)rwl;
  if (tid < 16) hist[tid] = 0;
  __syncthreads();

  if (q == 0) {
    unsigned packed = 0;
#pragma unroll
    for (int j = 0; j < 16; ++j) {
      int r = 0;
#pragma unroll
      for (int j2 = 0; j2 < 16; ++j2)
        r += (int)((p[j2] > p[j]) | ((p[j2] == p[j]) & (j2 < j)));
      if (r < KTOP) packed |= (unsigned)j << (8 * r);
    }
    tok_blocks[n] = packed;
    atomicAdd(&hist[packed & 15u], 1u);
    atomicAdd(&hist[(packed >> 8) & 15u], 1u);
    atomicAdd(&hist[(packed >> 16) & 15u], 1u);
    atomicAdd(&hist[(packed >> 24) & 15u], 1u);
  }
  __syncthreads();
  if (tid < 16 && hist[tid]) atomicAdd(&counts[tid], hist[tid]);
}

// ---------------- scan: padded offsets + cursors ----------------
__global__ void k_scan(const unsigned* __restrict__ counts, unsigned* __restrict__ off,
                       unsigned* __restrict__ cursors) {
  if (threadIdx.x == 0 && blockIdx.x == 0) {
    unsigned o = 0;
    for (int i = 0; i < 16; ++i) {
      off[i] = o; cursors[i] = o;
      o += (counts[i] + 127u) & ~127u;
    }
    off[16] = o;
  }
}

// ---------------- build per-block token lists + inverse map ----------------
__global__ __launch_bounds__(256) void k_build(
    const unsigned* __restrict__ tok_blocks, unsigned* __restrict__ cursors,
    unsigned short* __restrict__ list, unsigned* __restrict__ inv) {
  const int n = blockIdx.x * 256 + threadIdx.x;
  const unsigned packed = tok_blocks[n];
  const int lane = threadIdx.x & 63;
  for (int b = 0; b < 16; ++b) {
    int r = -1;
#pragma unroll
    for (int q = 0; q < 4; ++q)
      if (((packed >> (8 * q)) & 15u) == (unsigned)b) r = q;
    unsigned long long m = __ballot(r >= 0);
    if (m) {
      int leader = __ffsll((unsigned long long)m) - 1;
      unsigned base = 0;
      if (lane == leader) base = atomicAdd(&cursors[b], (unsigned)__popcll(m));
      base = (unsigned)__shfl((int)base, leader);
      if (r >= 0) {
        unsigned pos = base + (unsigned)__popcll(m & ((1ull << lane) - 1ull));
        list[pos] = (unsigned short)n;
        inv[(size_t)n * 4 + r] = pos;
      }
    }
  }
}

// ---------------- fc1: hg_c[prow][j] = relu(X@W1^T + b1) at pi-cols (bf16) ----------------
__global__ __launch_bounds__(256, 2) void k_fc1(
    const unsigned short* __restrict__ xb, const unsigned short* __restrict__ w1b,
    const float* __restrict__ b1p, const unsigned short* __restrict__ list,
    const unsigned* __restrict__ counts, const unsigned* __restrict__ off,
    unsigned short* __restrict__ hg) {
  const int bid0 = blockIdx.x;
  const int bid = (bid0 & 7) * 256 + (bid0 >> 3);   // XCD swizzle: same-blk tiles share an XCD
  const int blk = bid >> 7;
  const int tile = bid & 127;
  const unsigned cnt = counts[blk];
  if ((unsigned)(tile * 128) >= cnt) return;
  const unsigned goff = off[blk] + tile * 128;

  __shared__ __align__(16) unsigned short As[128 * 64];
  __shared__ __align__(16) unsigned short Bs[256 * 64];
  __shared__ unsigned toks[128];

  const int tid = threadIdx.x;
  const int lane = tid & 63;
  const int wid = tid >> 6;
  const int wr = wid >> 1, wc = wid & 1;

  if (tid < 128) toks[tid] = list[goff + tid];
  __syncthreads();

  unsigned tokr[4]; int arow[4];
#pragma unroll
  for (int r = 0; r < 4; ++r) { arow[r] = (r * 256 + tid) >> 3; tokr[r] = toks[arow[r]]; }
  const int asl = tid & 7;

  f32x4 acc[4][8] = {};

  for (int k0 = 0; k0 < 1024; k0 += 64) {
    __syncthreads();
#pragma unroll
    for (int r = 0; r < 4; ++r) {
      const int kcs = asl ^ (arow[r] & 7);
      load_lds16(xb + (size_t)tokr[r] * INF + k0 + kcs * 8,
                 (char*)As + (r * 256 + wid * 64) * 16);
    }
#pragma unroll
    for (int r = 0; r < 8; ++r) {
      const int row = (r * 256 + tid) >> 3;
      const int kcs = asl ^ (row & 7);
      load_lds16(w1b + ((size_t)(blk * 256 + row)) * INF + k0 + kcs * 8,
                 (char*)Bs + (r * 256 + wid * 64) * 16);
    }
    __syncthreads();
#pragma unroll
    for (int ks = 0; ks < 2; ++ks) {
      bf16x8 a[4], b[8];
#pragma unroll
      for (int mi = 0; mi < 4; ++mi) {
        const int row = wr * 64 + mi * 16 + (lane & 15);
        const int kc = ks * 4 + (lane >> 4);
        a[mi] = *(const bf16x8*)((const char*)As + row * 128 + ((kc ^ (row & 7)) << 4));
      }
#pragma unroll
      for (int ni = 0; ni < 8; ++ni) {
        const int row = wc * 128 + ni * 16 + (lane & 15);
        const int kc = ks * 4 + (lane >> 4);
        b[ni] = *(const bf16x8*)((const char*)Bs + row * 128 + ((kc ^ (row & 7)) << 4));
      }
#pragma unroll
      for (int mi = 0; mi < 4; ++mi)
#pragma unroll
        for (int ni = 0; ni < 8; ++ni)
          acc[mi][ni] = __builtin_amdgcn_mfma_f32_16x16x32_bf16(a[mi], b[ni], acc[mi][ni], 0, 0, 0);
    }
  }
  // epilogue: bias+relu, pack 8 ni-values -> one 16B store at pi-permuted cols
  const int c16 = lane & 15;
  const float4* bp = (const float4*)(b1p + blk * 256 + wc * 128 + c16 * 8);
  const float4 bv0 = bp[0], bv1 = bp[1];
  const float bvv[8] = {bv0.x, bv0.y, bv0.z, bv0.w, bv1.x, bv1.y, bv1.z, bv1.w};
#pragma unroll
  for (int mi = 0; mi < 4; ++mi) {
#pragma unroll
    for (int i = 0; i < 4; ++i) {
      const int row = wr * 64 + mi * 16 + (lane >> 4) * 4 + i;
      u16x8 w;
#pragma unroll
      for (int ni = 0; ni < 8; ++ni) {
        float v = acc[mi][ni][i] + bvv[ni];
        v = v > 0.f ? v : 0.f;
        w[ni] = f2bf(v);
      }
      *(u16x8*)(hg + (size_t)(goff + row) * 256 + wc * 128 + c16 * 8) = w;
    }
  }
}

// ---------------- fc2: part_c[prow][p] = h @ W2blk^T at pi-cols (bf16) ----------------
__global__ __launch_bounds__(256, 2) void k_fc2(
    const unsigned short* __restrict__ hg, const unsigned short* __restrict__ w2p,
    const unsigned* __restrict__ counts, const unsigned* __restrict__ off,
    unsigned short* __restrict__ part) {
  const int bid0 = blockIdx.x;
  const int bid = (bid0 & 7) * 256 + (bid0 >> 3);   // XCD swizzle
  const int blk = bid >> 7;
  const int tile = bid & 127;
  const unsigned cnt = counts[blk];
  if ((unsigned)(tile * 128) >= cnt) return;
  const unsigned goff = off[blk] + tile * 128;
  const int rem = (int)cnt - tile * 128;

  __shared__ __align__(16) unsigned short As[128 * 64];
  __shared__ __align__(16) unsigned short Bs[256 * 64];

  const int tid = threadIdx.x;
  const int lane = tid & 63;
  const int wid = tid >> 6;
  const int wr = wid >> 1, wc = wid & 1;
  const int asl = tid & 7;
  const int c16 = lane & 15;

  for (int ns = 0; ns < 4; ++ns) {
    f32x4 acc[4][8] = {};
    for (int k0 = 0; k0 < 256; k0 += 64) {
      __syncthreads();
#pragma unroll
      for (int r = 0; r < 4; ++r) {
        const int row = (r * 256 + tid) >> 3;
        const int kcs = asl ^ (row & 7);
        load_lds16(hg + (size_t)(goff + row) * BLKSZ + k0 + kcs * 8,
                   (char*)As + (r * 256 + wid * 64) * 16);
      }
#pragma unroll
      for (int r = 0; r < 8; ++r) {
        const int row = (r * 256 + tid) >> 3;
        const int kcs = asl ^ (row & 7);
        load_lds16(w2p + (size_t)(ns * 256 + row) * OUTF + blk * 256 + k0 + kcs * 8,
                   (char*)Bs + (r * 256 + wid * 64) * 16);
      }
      __syncthreads();
#pragma unroll
      for (int ks = 0; ks < 2; ++ks) {
        bf16x8 a[4], b[8];
#pragma unroll
        for (int mi = 0; mi < 4; ++mi) {
          const int row = wr * 64 + mi * 16 + (lane & 15);
          const int kc = ks * 4 + (lane >> 4);
          a[mi] = *(const bf16x8*)((const char*)As + row * 128 + ((kc ^ (row & 7)) << 4));
        }
#pragma unroll
        for (int ni = 0; ni < 8; ++ni) {
          const int row = wc * 128 + ni * 16 + (lane & 15);
          const int kc = ks * 4 + (lane >> 4);
          b[ni] = *(const bf16x8*)((const char*)Bs + row * 128 + ((kc ^ (row & 7)) << 4));
        }
#pragma unroll
        for (int mi = 0; mi < 4; ++mi)
#pragma unroll
          for (int ni = 0; ni < 8; ++ni)
            acc[mi][ni] = __builtin_amdgcn_mfma_f32_16x16x32_bf16(a[mi], b[ni], acc[mi][ni], 0, 0, 0);
      }
    }
    // epilogue: pack 8 ni-values -> one 16B store at pi-permuted cols (compact row index)
#pragma unroll
    for (int mi = 0; mi < 4; ++mi) {
#pragma unroll
      for (int i = 0; i < 4; ++i) {
        const int mrow = wr * 64 + mi * 16 + (lane >> 4) * 4 + i;
        if (mrow < rem) {
          u16x8 w;
#pragma unroll
          for (int ni = 0; ni < 8; ++ni) w[ni] = f2bf(acc[mi][ni][i]);
          *(u16x8*)(part + (size_t)(goff + mrow) * 1024 + ns * 256 + wc * 128 + c16 * 8) = w;
        }
      }
    }
  }
}

// ---------------- reduce: out[tok][c] = b2[c] + sum_s part_c[inv[tok][s]][sigma(c)] ----------------
__global__ __launch_bounds__(256) void k_reduce(const unsigned short* __restrict__ part,
                                                const unsigned* __restrict__ inv,
                                                const float* __restrict__ b2,
                                                float* __restrict__ out) {
  __shared__ float lds[8 * 1028];  // 8 tokens x 1024 (+4 pad)
  const int tid = threadIdx.x;
  const int tok0 = blockIdx.x * 8;
  const int tok_l = tid >> 5;
  const int l32 = tid & 31;

  const uint4 iv = *(const uint4*)(inv + (size_t)(tok0 + tok_l) * 4);
  const unsigned prow[4] = {iv.x, iv.y, iv.z, iv.w};

#pragma unroll
  for (int g = 0; g < 4; ++g) {
    const int idx = g * 32 + l32;          // p-group in [0,128)
    const int p0 = idx * 8;
    float s[8] = {0.f, 0.f, 0.f, 0.f, 0.f, 0.f, 0.f, 0.f};
#pragma unroll
    for (int sl = 0; sl < 4; ++sl) {
      u16x8 v = *(const u16x8*)(part + (size_t)prow[sl] * 1024 + p0);
#pragma unroll
      for (int j = 0; j < 8; ++j)
        s[j] += __uint_as_float((unsigned)(unsigned short)v[j] << 16);
    }
    const int ns = idx >> 5, wcb = (idx >> 4) & 1, cc = idx & 15;
#pragma unroll
    for (int ni = 0; ni < 8; ++ni)
      lds[tok_l * 1028 + ns * 256 + wcb * 128 + ni * 16 + cc] = s[ni];
  }
  __syncthreads();
  // write out coalesced, one token-row per round
  const float4 b2v = ((const float4*)b2)[tid];
#pragma unroll
  for (int r = 0; r < 8; ++r) {
    f32x4 lv = *(f32x4*)&lds[r * 1028 + tid * 4];
    float4 o = make_float4(lv[0] + b2v.x, lv[1] + b2v.y, lv[2] + b2v.z, lv[3] + b2v.w);
    *(float4*)(out + (size_t)(tok0 + r) * 1024 + tid * 4) = o;
  }
}

extern "C" void kernel_launch(void* const* d_in, const int* in_sizes, int n_in,
                              void* d_out, int out_size, void* d_ws, size_t ws_size,
                              hipStream_t stream) {
  const float* x  = (const float*)d_in[0];
  const float* rw = (const float*)d_in[1];
  const float* rb = (const float*)d_in[2];
  const float* w1 = (const float*)d_in[3];
  const float* b1 = (const float*)d_in[4];
  const float* w2 = (const float*)d_in[5];
  const float* b2 = (const float*)d_in[6];
  float* out = (float*)d_out;

  char* ws = (char*)d_ws;
  // part_c (138,412,032 B) overlays xb (32MB) + w1b (8MB): both dead before fc2 writes part.
  unsigned short* part = (unsigned short*)(ws);              // 138,412,032 B
  unsigned short* xb   = (unsigned short*)(ws);              // 33,554,432 B (alias)
  unsigned short* w1b  = (unsigned short*)(ws + 33554432);   //  8,388,608 B (alias)
  unsigned short* hg   = (unsigned short*)(ws + 138412032);  // 34,603,008 B
  unsigned short* w2p  = (unsigned short*)(ws + 173015040);  //  8,388,608 B
  unsigned* tokb       = (unsigned*)(ws + 181403648);        //     65,536 B
  unsigned short* list = (unsigned short*)(ws + 181469184);  //    135,168 B
  unsigned* inv        = (unsigned*)(ws + 181604352);        //    262,144 B
  float* b1p           = (float*)(ws + 181866496);           //     16,384 B
  unsigned* counts     = (unsigned*)(ws + 181882880);
  unsigned* off        = (unsigned*)(ws + 181882944);
  unsigned* cursors    = (unsigned*)(ws + 181883072);

  k_zero<<<dim3(133), dim3(256), 0, stream>>>((unsigned*)list, counts);
  k_convert<<<dim3(1024), dim3(256), 0, stream>>>(w1, w2, b1, w1b, w2p, b1p);
  k_router<<<dim3(512), dim3(256), 0, stream>>>(x, rw, rb, tokb, counts, xb);
  k_scan<<<dim3(1), dim3(64), 0, stream>>>(counts, off, cursors);
  k_build<<<dim3(64), dim3(256), 0, stream>>>(tokb, cursors, list, inv);
  k_fc1<<<dim3(2048), dim3(256), 0, stream>>>(xb, w1b, b1p, list, counts, off, hg);
  k_fc2<<<dim3(2048), dim3(256), 0, stream>>>(hg, w2p, counts, off, part);
  k_reduce<<<dim3(2048), dim3(256), 0, stream>>>(part, inv, b2, out);
}

// Round 5
// 292.451 us; speedup vs baseline: 1.8234x; 1.0824x over previous
//
#include <hip/hip_runtime.h>
#include <hip/hip_bf16.h>

#define NTOK   16384
#define INF    1024
#define OUTF   4096
#define NBLK   16
#define BLKSZ  256
#define KTOP   4

typedef short bf16x8 __attribute__((ext_vector_type(8)));
typedef float f32x4 __attribute__((ext_vector_type(4)));
typedef unsigned short u16x8 __attribute__((ext_vector_type(8)));

__device__ __forceinline__ unsigned short f2bf(float f) {
  unsigned u = __float_as_uint(f);
  u += 0x7FFFu + ((u >> 16) & 1u);
  return (unsigned short)(u >> 16);
}

__device__ __forceinline__ void load_lds16(const void* g, void* l) {
  __builtin_amdgcn_global_load_lds(
      (const __attribute__((address_space(1))) unsigned int*)g,
      (__attribute__((address_space(3))) unsigned int*)l, 16, 0, 0);
}

__device__ __forceinline__ double shfl_xor_d(double v, int m) {
  long long l = __double_as_longlong(v);
  int lo = (int)(l & 0xFFFFFFFFll), hi = (int)(l >> 32);
  lo = __shfl_xor(lo, m);
  hi = __shfl_xor(hi, m);
  return __longlong_as_double(((long long)hi << 32) | (unsigned long long)(unsigned)lo);
}

// pi(j): storage j = 128*wc + 8*c16 + ni  <->  original col = 128*wc + 16*ni + c16
__device__ __forceinline__ int pi_perm(int j) {
  return (j & 128) | ((j & 7) << 4) | ((j >> 3) & 15);
}

// ---------------- zero counts + list pad ----------------
__global__ void k_zero(unsigned* __restrict__ list32, unsigned* __restrict__ counts) {
  int i = blockIdx.x * 256 + threadIdx.x;
  if (i < 33792) list32[i] = 0;            // 67584 u16 entries
  else if (i < 33808) counts[i - 33792] = 0;
}

// ---------------- convert: w1->bf16 linear, w2->bf16 pi-permuted, b1p f32 permuted ----------------
__global__ __launch_bounds__(256) void k_convert(
    const float* __restrict__ w1, const float* __restrict__ w2,
    const float* __restrict__ b1, unsigned short* __restrict__ w1b,
    unsigned short* __restrict__ w2p, float* __restrict__ b1p) {
  const size_t stride = (size_t)gridDim.x * 256;
  for (size_t i = (size_t)blockIdx.x * 256 + threadIdx.x; i < 1573376; i += stride) {
    if (i < 1048576) {
      float4 v = ((const float4*)w1)[i];
      ushort4 o;
      o.x = f2bf(v.x); o.y = f2bf(v.y); o.z = f2bf(v.z); o.w = f2bf(v.w);
      ((ushort4*)w1b)[i] = o;
    } else if (i < 1572864) {
      const size_t g = i - 1048576;          // u16x8 group of w2p
      const int d = (int)(g >> 9);           // 512 groups per 4096-row
      const int rest = (int)(g & 511);
      const int jg = rest * 8;               // col group start in [0,4096)
      const int blk = jg >> 8;
      const int j0 = jg & 255;
      const float* src = w2 + (size_t)d * 4096 + blk * 256;
      u16x8 o;
#pragma unroll
      for (int ni = 0; ni < 8; ++ni) o[ni] = f2bf(src[pi_perm(j0 + ni)]);
      *(u16x8*)(w2p + (size_t)d * 4096 + jg) = o;
    } else {
      const int idx = (int)(i - 1572864);    // 512 groups of 8 for b1p
      const int jg = idx * 8;
      const int blk = jg >> 8;
      const int j0 = jg & 255;
      const float* src = b1 + blk * 256;
      float o[8];
#pragma unroll
      for (int ni = 0; ni < 8; ++ni) o[ni] = src[pi_perm(j0 + ni)];
      float4* dst = (float4*)(b1p + jg);
      dst[0] = make_float4(o[0], o[1], o[2], o[3]);
      dst[1] = make_float4(o[4], o[5], o[6], o[7]);
    }
  }
}

// ---------------- router: logits (f64, 8 lanes/token), top-4, counts, x->bf16 ----------------
__global__ __launch_bounds__(256) void k_router(
    const float* __restrict__ x, const float* __restrict__ rw,
    const float* __restrict__ rb, unsigned* __restrict__ tok_blocks,
    unsigned* __restrict__ counts, unsigned short* __restrict__ xb) {
  __shared__ float4 rwl[4096];  // full router_w [16][1024] fp32 = 64KB (reused as hist after)
  const int tid = threadIdx.x;
  const float4* rw4 = (const float4*)rw;
  for (int i = tid; i < 4096; i += 256) rwl[i] = rw4[i];
  __syncthreads();

  const int n = blockIdx.x * 32 + (tid >> 3);
  const int q = tid & 7;
  double p[16];
#pragma unroll
  for (int j = 0; j < 16; ++j) p[j] = 0.0;
  const float4* xr = (const float4*)(x + (size_t)n * INF);
  ushort4* xbr = (ushort4*)(xb + (size_t)n * INF);
#pragma unroll 4
  for (int i = 0; i < 32; ++i) {
    const int d4 = q + i * 8;
    const float4 xv = xr[d4];
    ushort4 o;
    o.x = f2bf(xv.x); o.y = f2bf(xv.y); o.z = f2bf(xv.z); o.w = f2bf(xv.w);
    xbr[d4] = o;
#pragma unroll
    for (int j = 0; j < 16; ++j) {
      const float4 wv = rwl[j * 256 + d4];
      p[j] = fma((double)xv.x, (double)wv.x, p[j]);
      p[j] = fma((double)xv.y, (double)wv.y, p[j]);
      p[j] = fma((double)xv.z, (double)wv.z, p[j]);
      p[j] = fma((double)xv.w, (double)wv.w, p[j]);
    }
  }
#pragma unroll
  for (int j = 0; j < 16; ++j) {
    double v = p[j];
    v += shfl_xor_d(v, 1);
    v += shfl_xor_d(v, 2);
    v += shfl_xor_d(v, 4);
    p[j] = v + (double)rb[j];
  }

  __syncthreads();
  unsigned* hist = (unsigned*)rwl;
  if (tid < 16) hist[tid] = 0;
  __syncthreads();

  if (q == 0) {
    unsigned packed = 0;
#pragma unroll
    for (int j = 0; j < 16; ++j) {
      int r = 0;
#pragma unroll
      for (int j2 = 0; j2 < 16; ++j2)
        r += (int)((p[j2] > p[j]) | ((p[j2] == p[j]) & (j2 < j)));
      if (r < KTOP) packed |= (unsigned)j << (8 * r);
    }
    tok_blocks[n] = packed;
    atomicAdd(&hist[packed & 15u], 1u);
    atomicAdd(&hist[(packed >> 8) & 15u], 1u);
    atomicAdd(&hist[(packed >> 16) & 15u], 1u);
    atomicAdd(&hist[(packed >> 24) & 15u], 1u);
  }
  __syncthreads();
  if (tid < 16 && hist[tid]) atomicAdd(&counts[tid], hist[tid]);
}

// ---------------- scan: padded offsets + cursors ----------------
__global__ void k_scan(const unsigned* __restrict__ counts, unsigned* __restrict__ off,
                       unsigned* __restrict__ cursors) {
  if (threadIdx.x == 0 && blockIdx.x == 0) {
    unsigned o = 0;
    for (int i = 0; i < 16; ++i) {
      off[i] = o; cursors[i] = o;
      o += (counts[i] + 127u) & ~127u;
    }
    off[16] = o;
  }
}

// ---------------- build per-block token lists + inverse map ----------------
__global__ __launch_bounds__(256) void k_build(
    const unsigned* __restrict__ tok_blocks, unsigned* __restrict__ cursors,
    unsigned short* __restrict__ list, unsigned* __restrict__ inv) {
  const int n = blockIdx.x * 256 + threadIdx.x;
  const unsigned packed = tok_blocks[n];
  const int lane = threadIdx.x & 63;
  for (int b = 0; b < 16; ++b) {
    int r = -1;
#pragma unroll
    for (int q = 0; q < 4; ++q)
      if (((packed >> (8 * q)) & 15u) == (unsigned)b) r = q;
    unsigned long long m = __ballot(r >= 0);
    if (m) {
      int leader = __ffsll((unsigned long long)m) - 1;
      unsigned base = 0;
      if (lane == leader) base = atomicAdd(&cursors[b], (unsigned)__popcll(m));
      base = (unsigned)__shfl((int)base, leader);
      if (r >= 0) {
        unsigned pos = base + (unsigned)__popcll(m & ((1ull << lane) - 1ull));
        list[pos] = (unsigned short)n;
        inv[(size_t)n * 4 + r] = pos;
      }
    }
  }
}

// ---------------- fused FFN: per 128-row tile, h stays in LDS ----------------
// Phase A: h = relu(Xg @ W1blk^T + b1) -> LDS (pi-permuted, XOR-swizzled)
// Phase B: part[goff+row] = h @ W2blk^T (pi-cols), full-line bf16 stores
__global__ __launch_bounds__(512, 1) void k_ffn(
    const unsigned short* __restrict__ xb, const unsigned short* __restrict__ w1b,
    const unsigned short* __restrict__ w2p, const float* __restrict__ b1p,
    const unsigned short* __restrict__ list, const unsigned* __restrict__ counts,
    const unsigned* __restrict__ off, unsigned short* __restrict__ part) {
  // LDS: [0,64K) h tile; [64K,80K) As (fc1); [80K,112K) Bs (fc1); Bs2 aliases [64K,96K)
  __shared__ __align__(16) char lds[114688];
  char* As  = lds + 65536;
  char* Bs  = lds + 81920;
  char* Bs2 = lds + 65536;
  __shared__ unsigned toks[128];

  const int bid0 = blockIdx.x;
  const int bid = (bid0 & 7) * 256 + (bid0 >> 3);   // XCD swizzle: same-expert tiles share an XCD
  const int blk = bid >> 7;
  const int tile = bid & 127;
  const unsigned cnt = counts[blk];
  if ((unsigned)(tile * 128) >= cnt) return;
  const unsigned goff = off[blk] + tile * 128;

  const int tid = threadIdx.x;
  const int lane = tid & 63;
  const int wid = tid >> 6;      // 0..7
  const int wr = wid >> 1;       // 0..3 : rows wr*32..+32
  const int wc = wid & 1;        // 0..1 : cols wc*128..+128
  const int asl = tid & 7;
  const int c16 = lane & 15;

  if (tid < 128) toks[tid] = list[goff + tid];
  __syncthreads();

  const unsigned tok0 = toks[tid >> 3];
  const unsigned tok1 = toks[64 + (tid >> 3)];

  // -------- phase A: fc1 --------
  f32x4 acc[2][8] = {};
  for (int k0 = 0; k0 < 1024; k0 += 64) {
    {
      const int row0 = tid >> 3;
      const int kcs0 = asl ^ (row0 & 7);
      load_lds16(xb + (size_t)tok0 * INF + k0 + kcs0 * 8, As + (wid * 64) * 16);
      const int row1 = 64 + row0;
      const int kcs1 = asl ^ (row1 & 7);
      load_lds16(xb + (size_t)tok1 * INF + k0 + kcs1 * 8, As + (512 + wid * 64) * 16);
    }
#pragma unroll
    for (int r = 0; r < 4; ++r) {
      const int row = (r * 512 + tid) >> 3;
      const int kcs = asl ^ (row & 7);
      load_lds16(w1b + ((size_t)(blk * 256 + row)) * INF + k0 + kcs * 8,
                 Bs + (r * 512 + wid * 64) * 16);
    }
    __syncthreads();
#pragma unroll
    for (int ks = 0; ks < 2; ++ks) {
      const int kc = ks * 4 + (lane >> 4);
      bf16x8 a[2], b[8];
#pragma unroll
      for (int mi = 0; mi < 2; ++mi) {
        const int row = wr * 32 + mi * 16 + (lane & 15);
        a[mi] = *(const bf16x8*)(As + row * 128 + ((kc ^ (row & 7)) << 4));
      }
#pragma unroll
      for (int ni = 0; ni < 8; ++ni) {
        const int row = wc * 128 + ni * 16 + (lane & 15);
        b[ni] = *(const bf16x8*)(Bs + row * 128 + ((kc ^ (row & 7)) << 4));
      }
#pragma unroll
      for (int mi = 0; mi < 2; ++mi)
#pragma unroll
        for (int ni = 0; ni < 8; ++ni)
          acc[mi][ni] = __builtin_amdgcn_mfma_f32_16x16x32_bf16(a[mi], b[ni], acc[mi][ni], 0, 0, 0);
    }
    __syncthreads();
  }

  // h = relu(acc + b1) -> LDS, pi-permuted cols, XOR-swizzled 16B chunks (row stride 512B)
  {
    const float4* bp = (const float4*)(b1p + blk * 256 + wc * 128 + c16 * 8);
    const float4 bv0 = bp[0], bv1 = bp[1];
    const float bvv[8] = {bv0.x, bv0.y, bv0.z, bv0.w, bv1.x, bv1.y, bv1.z, bv1.w};
    const int chunk = wc * 16 + c16;  // 0..31
    const int cslot = (chunk & ~7);
    const int clow  = (chunk & 7);
#pragma unroll
    for (int mi = 0; mi < 2; ++mi) {
#pragma unroll
      for (int i = 0; i < 4; ++i) {
        const int row = wr * 32 + mi * 16 + (lane >> 4) * 4 + i;
        u16x8 wv;
#pragma unroll
        for (int ni = 0; ni < 8; ++ni) {
          float v = acc[mi][ni][i] + bvv[ni];
          v = v > 0.f ? v : 0.f;
          wv[ni] = f2bf(v);
        }
        *(u16x8*)(lds + row * 512 + ((cslot | (clow ^ (row & 7))) << 4)) = wv;
      }
    }
  }
  __syncthreads();  // h visible to all; As/Bs dead -> Bs2 alias safe

  // -------- phase B: fc2 --------
  for (int ns = 0; ns < 4; ++ns) {
    f32x4 acc2[2][8] = {};
    for (int k0 = 0; k0 < 256; k0 += 64) {
#pragma unroll
      for (int r = 0; r < 4; ++r) {
        const int row = (r * 512 + tid) >> 3;   // d-row within ns group, 0..255
        const int kcs = asl ^ (row & 7);
        load_lds16(w2p + (size_t)(ns * 256 + row) * OUTF + blk * 256 + k0 + kcs * 8,
                   Bs2 + (r * 512 + wid * 64) * 16);
      }
      __syncthreads();
#pragma unroll
      for (int ks = 0; ks < 2; ++ks) {
        const int kc = ks * 4 + (lane >> 4);
        bf16x8 a[2], b[8];
#pragma unroll
        for (int mi = 0; mi < 2; ++mi) {
          const int row = wr * 32 + mi * 16 + (lane & 15);
          a[mi] = *(const bf16x8*)(lds + row * 512 + k0 * 2 + ((kc ^ (row & 7)) << 4));
        }
#pragma unroll
        for (int ni = 0; ni < 8; ++ni) {
          const int row = wc * 128 + ni * 16 + (lane & 15);
          b[ni] = *(const bf16x8*)(Bs2 + row * 128 + ((kc ^ (row & 7)) << 4));
        }
#pragma unroll
        for (int mi = 0; mi < 2; ++mi)
#pragma unroll
          for (int ni = 0; ni < 8; ++ni)
            acc2[mi][ni] = __builtin_amdgcn_mfma_f32_16x16x32_bf16(a[mi], b[ni], acc2[mi][ni], 0, 0, 0);
      }
      __syncthreads();
    }
    // epilogue: pi-packed full-line stores (pad rows written too; never read)
#pragma unroll
    for (int mi = 0; mi < 2; ++mi) {
#pragma unroll
      for (int i = 0; i < 4; ++i) {
        const int row = wr * 32 + mi * 16 + (lane >> 4) * 4 + i;
        u16x8 wv;
#pragma unroll
        for (int ni = 0; ni < 8; ++ni) wv[ni] = f2bf(acc2[mi][ni][i]);
        *(u16x8*)(part + (size_t)(goff + row) * 1024 + ns * 256 + wc * 128 + c16 * 8) = wv;
      }
    }
  }
}

// ---------------- reduce: out[tok][c] = b2[c] + sum_s part_c[inv[tok][s]][sigma(c)] ----------------
__global__ __launch_bounds__(256) void k_reduce(const unsigned short* __restrict__ part,
                                                const unsigned* __restrict__ inv,
                                                const float* __restrict__ b2,
                                                float* __restrict__ out) {
  __shared__ float lds[8 * 1028];  // 8 tokens x 1024 (+4 pad)
  const int tid = threadIdx.x;
  const int tok0 = blockIdx.x * 8;
  const int tok_l = tid >> 5;
  const int l32 = tid & 31;

  const uint4 iv = *(const uint4*)(inv + (size_t)(tok0 + tok_l) * 4);
  const unsigned prow[4] = {iv.x, iv.y, iv.z, iv.w};

#pragma unroll
  for (int g = 0; g < 4; ++g) {
    const int idx = g * 32 + l32;          // p-group in [0,128)
    const int p0 = idx * 8;
    float s[8] = {0.f, 0.f, 0.f, 0.f, 0.f, 0.f, 0.f, 0.f};
#pragma unroll
    for (int sl = 0; sl < 4; ++sl) {
      u16x8 v = *(const u16x8*)(part + (size_t)prow[sl] * 1024 + p0);
#pragma unroll
      for (int j = 0; j < 8; ++j)
        s[j] += __uint_as_float((unsigned)(unsigned short)v[j] << 16);
    }
    const int ns = idx >> 5, wcb = (idx >> 4) & 1, cc = idx & 15;
#pragma unroll
    for (int ni = 0; ni < 8; ++ni)
      lds[tok_l * 1028 + ns * 256 + wcb * 128 + ni * 16 + cc] = s[ni];
  }
  __syncthreads();
  // write out coalesced, one token-row per round
  const float4 b2v = ((const float4*)b2)[tid];
#pragma unroll
  for (int r = 0; r < 8; ++r) {
    f32x4 lv = *(f32x4*)&lds[r * 1028 + tid * 4];
    float4 o = make_float4(lv[0] + b2v.x, lv[1] + b2v.y, lv[2] + b2v.z, lv[3] + b2v.w);
    *(float4*)(out + (size_t)(tok0 + r) * 1024 + tid * 4) = o;
  }
}

extern "C" void kernel_launch(void* const* d_in, const int* in_sizes, int n_in,
                              void* d_out, int out_size, void* d_ws, size_t ws_size,
                              hipStream_t stream) {
  const float* x  = (const float*)d_in[0];
  const float* rw = (const float*)d_in[1];
  const float* rb = (const float*)d_in[2];
  const float* w1 = (const float*)d_in[3];
  const float* b1 = (const float*)d_in[4];
  const float* w2 = (const float*)d_in[5];
  const float* b2 = (const float*)d_in[6];
  float* out = (float*)d_out;

  char* ws = (char*)d_ws;
  // no aliasing: part is written while xb is still being read (same fused kernel)
  unsigned short* part = (unsigned short*)(ws);              // 138,412,032 B
  unsigned short* xb   = (unsigned short*)(ws + 138412032);  //  33,554,432 B
  unsigned short* w1b  = (unsigned short*)(ws + 171966464);  //   8,388,608 B
  unsigned short* w2p  = (unsigned short*)(ws + 180355072);  //   8,388,608 B
  unsigned* tokb       = (unsigned*)(ws + 188743680);        //      65,536 B
  unsigned short* list = (unsigned short*)(ws + 188809216);  //     135,168 B
  unsigned* inv        = (unsigned*)(ws + 188944384);        //     262,144 B
  float* b1p           = (float*)(ws + 189206528);           //      16,384 B
  unsigned* counts     = (unsigned*)(ws + 189222912);
  unsigned* off        = (unsigned*)(ws + 189222976);
  unsigned* cursors    = (unsigned*)(ws + 189223104);

  k_zero<<<dim3(133), dim3(256), 0, stream>>>((unsigned*)list, counts);
  k_convert<<<dim3(1024), dim3(256), 0, stream>>>(w1, w2, b1, w1b, w2p, b1p);
  k_router<<<dim3(512), dim3(256), 0, stream>>>(x, rw, rb, tokb, counts, xb);
  k_scan<<<dim3(1), dim3(64), 0, stream>>>(counts, off, cursors);
  k_build<<<dim3(64), dim3(256), 0, stream>>>(tokb, cursors, list, inv);
  k_ffn<<<dim3(2048), dim3(512), 0, stream>>>(xb, w1b, w2p, b1p, list, counts, off, part);
  k_reduce<<<dim3(2048), dim3(256), 0, stream>>>(part, inv, b2, out);
}

// Round 6
// 266.682 us; speedup vs baseline: 1.9996x; 1.0966x over previous
//
#include <hip/hip_runtime.h>
#include <hip/hip_bf16.h>

#define NTOK   16384
#define INF    1024
#define OUTF   4096
#define NBLK   16
#define BLKSZ  256
#define KTOP   4

typedef short bf16x8 __attribute__((ext_vector_type(8)));
typedef float f32x4 __attribute__((ext_vector_type(4)));
typedef unsigned short u16x8 __attribute__((ext_vector_type(8)));

__device__ __forceinline__ unsigned short f2bf(float f) {
  unsigned u = __float_as_uint(f);
  u += 0x7FFFu + ((u >> 16) & 1u);
  return (unsigned short)(u >> 16);
}

__device__ __forceinline__ void load_lds16(const void* g, void* l) {
  __builtin_amdgcn_global_load_lds(
      (const __attribute__((address_space(1))) unsigned int*)g,
      (__attribute__((address_space(3))) unsigned int*)l, 16, 0, 0);
}

__device__ __forceinline__ double shfl_xor_d(double v, int m) {
  long long l = __double_as_longlong(v);
  int lo = (int)(l & 0xFFFFFFFFll), hi = (int)(l >> 32);
  lo = __shfl_xor(lo, m);
  hi = __shfl_xor(hi, m);
  return __longlong_as_double(((long long)hi << 32) | (unsigned long long)(unsigned)lo);
}

// pi(j): storage j = 128*wc + 8*c16 + ni  <->  original col = 128*wc + 16*ni + c16
__device__ __forceinline__ int pi_perm(int j) {
  return (j & 128) | ((j & 7) << 4) | ((j >> 3) & 15);
}

// ---------------- zero counts + list pad ----------------
__global__ void k_zero(unsigned* __restrict__ list32, unsigned* __restrict__ counts) {
  int i = blockIdx.x * 256 + threadIdx.x;
  if (i < 33792) list32[i] = 0;            // 67584 u16 entries
  else if (i < 33808) counts[i - 33792] = 0;
}

// ---------------- convert: w1->bf16 linear, w2->bf16 pi-permuted, b1p f32 permuted ----------------
__global__ __launch_bounds__(256) void k_convert(
    const float* __restrict__ w1, const float* __restrict__ w2,
    const float* __restrict__ b1, unsigned short* __restrict__ w1b,
    unsigned short* __restrict__ w2p, float* __restrict__ b1p) {
  const size_t stride = (size_t)gridDim.x * 256;
  for (size_t i = (size_t)blockIdx.x * 256 + threadIdx.x; i < 1573376; i += stride) {
    if (i < 1048576) {
      float4 v = ((const float4*)w1)[i];
      ushort4 o;
      o.x = f2bf(v.x); o.y = f2bf(v.y); o.z = f2bf(v.z); o.w = f2bf(v.w);
      ((ushort4*)w1b)[i] = o;
    } else if (i < 1572864) {
      const size_t g = i - 1048576;          // u16x8 group of w2p
      const int d = (int)(g >> 9);           // 512 groups per 4096-row
      const int rest = (int)(g & 511);
      const int jg = rest * 8;               // col group start in [0,4096)
      const int blk = jg >> 8;
      const int j0 = jg & 255;
      const float* src = w2 + (size_t)d * 4096 + blk * 256;
      u16x8 o;
#pragma unroll
      for (int ni = 0; ni < 8; ++ni) o[ni] = f2bf(src[pi_perm(j0 + ni)]);
      *(u16x8*)(w2p + (size_t)d * 4096 + jg) = o;
    } else {
      const int idx = (int)(i - 1572864);    // 512 groups of 8 for b1p
      const int jg = idx * 8;
      const int blk = jg >> 8;
      const int j0 = jg & 255;
      const float* src = b1 + blk * 256;
      float o[8];
#pragma unroll
      for (int ni = 0; ni < 8; ++ni) o[ni] = src[pi_perm(j0 + ni)];
      float4* dst = (float4*)(b1p + jg);
      dst[0] = make_float4(o[0], o[1], o[2], o[3]);
      dst[1] = make_float4(o[4], o[5], o[6], o[7]);
    }
  }
}

// ---------------- router: logits (f64, 8 lanes/token), top-4, counts, x->bf16 ----------------
__global__ __launch_bounds__(256) void k_router(
    const float* __restrict__ x, const float* __restrict__ rw,
    const float* __restrict__ rb, unsigned* __restrict__ tok_blocks,
    unsigned* __restrict__ counts, unsigned short* __restrict__ xb) {
  __shared__ float4 rwl[4096];  // full router_w [16][1024] fp32 = 64KB (reused as hist after)
  const int tid = threadIdx.x;
  const float4* rw4 = (const float4*)rw;
  for (int i = tid; i < 4096; i += 256) rwl[i] = rw4[i];
  __syncthreads();

  const int n = blockIdx.x * 32 + (tid >> 3);
  const int q = tid & 7;
  double p[16];
#pragma unroll
  for (int j = 0; j < 16; ++j) p[j] = 0.0;
  const float4* xr = (const float4*)(x + (size_t)n * INF);
  ushort4* xbr = (ushort4*)(xb + (size_t)n * INF);
#pragma unroll 4
  for (int i = 0; i < 32; ++i) {
    const int d4 = q + i * 8;
    const float4 xv = xr[d4];
    ushort4 o;
    o.x = f2bf(xv.x); o.y = f2bf(xv.y); o.z = f2bf(xv.z); o.w = f2bf(xv.w);
    xbr[d4] = o;
#pragma unroll
    for (int j = 0; j < 16; ++j) {
      const float4 wv = rwl[j * 256 + d4];
      p[j] = fma((double)xv.x, (double)wv.x, p[j]);
      p[j] = fma((double)xv.y, (double)wv.y, p[j]);
      p[j] = fma((double)xv.z, (double)wv.z, p[j]);
      p[j] = fma((double)xv.w, (double)wv.w, p[j]);
    }
  }
#pragma unroll
  for (int j = 0; j < 16; ++j) {
    double v = p[j];
    v += shfl_xor_d(v, 1);
    v += shfl_xor_d(v, 2);
    v += shfl_xor_d(v, 4);
    p[j] = v + (double)rb[j];
  }

  __syncthreads();
  unsigned* hist = (unsigned*)rwl;
  if (tid < 16) hist[tid] = 0;
  __syncthreads();

  if (q == 0) {
    unsigned packed = 0;
#pragma unroll
    for (int j = 0; j < 16; ++j) {
      int r = 0;
#pragma unroll
      for (int j2 = 0; j2 < 16; ++j2)
        r += (int)((p[j2] > p[j]) | ((p[j2] == p[j]) & (j2 < j)));
      if (r < KTOP) packed |= (unsigned)j << (8 * r);
    }
    tok_blocks[n] = packed;
    atomicAdd(&hist[packed & 15u], 1u);
    atomicAdd(&hist[(packed >> 8) & 15u], 1u);
    atomicAdd(&hist[(packed >> 16) & 15u], 1u);
    atomicAdd(&hist[(packed >> 24) & 15u], 1u);
  }
  __syncthreads();
  if (tid < 16 && hist[tid]) atomicAdd(&counts[tid], hist[tid]);
}

// ---------------- scan: padded offsets + cursors ----------------
__global__ void k_scan(const unsigned* __restrict__ counts, unsigned* __restrict__ off,
                       unsigned* __restrict__ cursors) {
  if (threadIdx.x == 0 && blockIdx.x == 0) {
    unsigned o = 0;
    for (int i = 0; i < 16; ++i) {
      off[i] = o; cursors[i] = o;
      o += (counts[i] + 127u) & ~127u;
    }
    off[16] = o;
  }
}

// ---------------- build per-block token lists + inverse map ----------------
__global__ __launch_bounds__(256) void k_build(
    const unsigned* __restrict__ tok_blocks, unsigned* __restrict__ cursors,
    unsigned short* __restrict__ list, unsigned* __restrict__ inv) {
  const int n = blockIdx.x * 256 + threadIdx.x;
  const unsigned packed = tok_blocks[n];
  const int lane = threadIdx.x & 63;
  for (int b = 0; b < 16; ++b) {
    int r = -1;
#pragma unroll
    for (int q = 0; q < 4; ++q)
      if (((packed >> (8 * q)) & 15u) == (unsigned)b) r = q;
    unsigned long long m = __ballot(r >= 0);
    if (m) {
      int leader = __ffsll((unsigned long long)m) - 1;
      unsigned base = 0;
      if (lane == leader) base = atomicAdd(&cursors[b], (unsigned)__popcll(m));
      base = (unsigned)__shfl((int)base, leader);
      if (r >= 0) {
        unsigned pos = base + (unsigned)__popcll(m & ((1ull << lane) - 1ull));
        list[pos] = (unsigned short)n;
        inv[(size_t)n * 4 + r] = pos;
      }
    }
  }
}

// ---------------- fused FFN with double-buffered prefetch staging ----------------
// Phase A: h = relu(Xg @ W1blk^T + b1) -> LDS (pi-permuted, XOR-swizzled)
// Phase B: part[goff+row] = h @ W2blk^T (pi-cols), full-line bf16 stores
// Schedule per step: STAGE(next buf) ; compute(cur buf) ; __syncthreads()
//   -> the syncthreads' vmcnt(0) drain lands AFTER the MFMA block, so HBM
//      latency overlaps compute. Buffer written at step t was last read at
//      step t-2 and sealed by the t-1 barrier: race-free with ONE barrier/step.
__global__ __launch_bounds__(512, 1) void k_ffn(
    const unsigned short* __restrict__ xb, const unsigned short* __restrict__ w1b,
    const unsigned short* __restrict__ w2p, const float* __restrict__ b1p,
    const unsigned short* __restrict__ list, const unsigned* __restrict__ counts,
    const unsigned* __restrict__ off, unsigned short* __restrict__ part) {
  // LDS: [0,64K) h ; As0 @64K, As1 @80K (16K each) ; Bs0 @96K, Bs1 @128K (32K each)
  __shared__ __align__(16) char lds[163840];
  char* const As0 = lds + 65536;
  char* const As1 = lds + 81920;
  char* const Bs0 = lds + 98304;
  char* const Bs1 = lds + 131072;

  const int bid0 = blockIdx.x;
  const int bid = (bid0 & 7) * 256 + (bid0 >> 3);   // XCD swizzle: same-expert tiles share an XCD
  const int blk = bid >> 7;
  const int tile = bid & 127;
  const unsigned cnt = counts[blk];
  if ((unsigned)(tile * 128) >= cnt) return;
  const unsigned goff = off[blk] + tile * 128;

  const int tid = threadIdx.x;
  const int lane = tid & 63;
  const int wid = tid >> 6;      // 0..7
  const int wr = wid >> 1;       // 0..3 : rows wr*32..+32
  const int wc = wid & 1;        // 0..1 : cols wc*128..+128
  const int asl = tid & 7;
  const int c16 = lane & 15;

  // token rows this thread stages (replaces LDS toks[])
  const unsigned tok0 = list[goff + (tid >> 3)];
  const unsigned tok1 = list[goff + 64 + (tid >> 3)];
  const int arow0 = tid >> 3;
  const int arow1 = 64 + arow0;

#define STAGE_A(buf, k0)                                                        \
  {                                                                             \
    load_lds16(xb + (size_t)tok0 * INF + (k0) + (asl ^ (arow0 & 7)) * 8,        \
               (buf) + (wid * 64) * 16);                                        \
    load_lds16(xb + (size_t)tok1 * INF + (k0) + (asl ^ (arow1 & 7)) * 8,        \
               (buf) + (512 + wid * 64) * 16);                                  \
  }

#define STAGE_B1(buf, k0)                                                       \
  _Pragma("unroll")                                                             \
  for (int r = 0; r < 4; ++r) {                                                 \
    const int row = (r * 512 + tid) >> 3;                                       \
    load_lds16(w1b + ((size_t)(blk * 256 + row)) * INF + (k0) +                 \
                   (asl ^ (row & 7)) * 8,                                       \
               (buf) + (r * 512 + wid * 64) * 16);                              \
  }

#define COMPUTE_A(abuf, bbuf)                                                   \
  _Pragma("unroll")                                                             \
  for (int ks = 0; ks < 2; ++ks) {                                              \
    const int kc = ks * 4 + (lane >> 4);                                        \
    bf16x8 a[2], b[8];                                                          \
    _Pragma("unroll")                                                           \
    for (int mi = 0; mi < 2; ++mi) {                                            \
      const int row = wr * 32 + mi * 16 + (lane & 15);                          \
      a[mi] = *(const bf16x8*)((abuf) + row * 128 + ((kc ^ (row & 7)) << 4));   \
    }                                                                           \
    _Pragma("unroll")                                                           \
    for (int ni = 0; ni < 8; ++ni) {                                            \
      const int row = wc * 128 + ni * 16 + (lane & 15);                         \
      b[ni] = *(const bf16x8*)((bbuf) + row * 128 + ((kc ^ (row & 7)) << 4));   \
    }                                                                           \
    _Pragma("unroll")                                                           \
    for (int mi = 0; mi < 2; ++mi)                                              \
      _Pragma("unroll")                                                         \
      for (int ni = 0; ni < 8; ++ni)                                            \
        acc[mi][ni] =                                                           \
            __builtin_amdgcn_mfma_f32_16x16x32_bf16(a[mi], b[ni], acc[mi][ni], 0, 0, 0); \
  }

  // -------- phase A: fc1 --------
  f32x4 acc[2][8] = {};
  STAGE_A(As0, 0);
  STAGE_B1(Bs0, 0);
  __syncthreads();
#pragma unroll 1
  for (int kk = 0; kk < 8; ++kk) {
    const int k0 = kk * 128;
    // even step: consume buf0, stage buf1 @ k0+64 (always valid: k0+64 <= 960)
    STAGE_A(As1, k0 + 64);
    STAGE_B1(Bs1, k0 + 64);
    COMPUTE_A(As0, Bs0);
    __syncthreads();
    // odd step: consume buf1, stage buf0 @ k0+128
    if (kk < 7) {
      STAGE_A(As0, k0 + 128);
      STAGE_B1(Bs0, k0 + 128);
    }
    COMPUTE_A(As1, Bs1);
    __syncthreads();
  }

#define STAGE_B2(buf, it)                                                       \
  {                                                                             \
    const int ns2 = (it) >> 2, k02 = ((it) & 3) * 64;                           \
    _Pragma("unroll")                                                           \
    for (int r = 0; r < 4; ++r) {                                               \
      const int row = (r * 512 + tid) >> 3;                                     \
      load_lds16(w2p + (size_t)(ns2 * 256 + row) * OUTF + blk * 256 + k02 +     \
                     (asl ^ (row & 7)) * 8,                                     \
                 (buf) + (r * 512 + wid * 64) * 16);                            \
    }                                                                           \
  }

#define COMPUTE_B(bbuf, k02)                                                    \
  _Pragma("unroll")                                                             \
  for (int ks = 0; ks < 2; ++ks) {                                              \
    const int kc = ks * 4 + (lane >> 4);                                        \
    bf16x8 a[2], b[8];                                                          \
    _Pragma("unroll")                                                           \
    for (int mi = 0; mi < 2; ++mi) {                                            \
      const int row = wr * 32 + mi * 16 + (lane & 15);                          \
      a[mi] = *(const bf16x8*)(lds + row * 512 + (k02) * 2 +                    \
                               ((kc ^ (row & 7)) << 4));                        \
    }                                                                           \
    _Pragma("unroll")                                                           \
    for (int ni = 0; ni < 8; ++ni) {                                            \
      const int row = wc * 128 + ni * 16 + (lane & 15);                         \
      b[ni] = *(const bf16x8*)((bbuf) + row * 128 + ((kc ^ (row & 7)) << 4));   \
    }                                                                           \
    _Pragma("unroll")                                                           \
    for (int mi = 0; mi < 2; ++mi)                                              \
      _Pragma("unroll")                                                         \
      for (int ni = 0; ni < 8; ++ni)                                            \
        acc2[mi][ni] =                                                          \
            __builtin_amdgcn_mfma_f32_16x16x32_bf16(a[mi], b[ni], acc2[mi][ni], 0, 0, 0); \
  }

  // stage phase-B's first tile while h is being written (Bs0 is dead now)
  STAGE_B2(Bs0, 0);

  // h = relu(acc + b1) -> LDS, pi-permuted cols, XOR-swizzled 16B chunks (row stride 512B)
  {
    const float4* bp = (const float4*)(b1p + blk * 256 + wc * 128 + c16 * 8);
    const float4 bv0 = bp[0], bv1 = bp[1];
    const float bvv[8] = {bv0.x, bv0.y, bv0.z, bv0.w, bv1.x, bv1.y, bv1.z, bv1.w};
    const int chunk = wc * 16 + c16;  // 0..31
    const int cslot = (chunk & ~7);
    const int clow  = (chunk & 7);
#pragma unroll
    for (int mi = 0; mi < 2; ++mi) {
#pragma unroll
      for (int i = 0; i < 4; ++i) {
        const int row = wr * 32 + mi * 16 + (lane >> 4) * 4 + i;
        u16x8 wv;
#pragma unroll
        for (int ni = 0; ni < 8; ++ni) {
          float v = acc[mi][ni][i] + bvv[ni];
          v = v > 0.f ? v : 0.f;
          wv[ni] = f2bf(v);
        }
        *(u16x8*)(lds + row * 512 + ((cslot | (clow ^ (row & 7))) << 4)) = wv;
      }
    }
  }
  __syncthreads();  // h visible; Bs0's it=0 data drained

  // -------- phase B: fc2 --------
#pragma unroll 1
  for (int ns = 0; ns < 4; ++ns) {
    f32x4 acc2[2][8] = {};
    const int it0 = ns * 4;
    // step it0: consume Bs0, stage it0+1 -> Bs1
    STAGE_B2(Bs1, it0 + 1);
    COMPUTE_B(Bs0, 0);
    __syncthreads();
    // step it0+1: consume Bs1, stage it0+2 -> Bs0
    STAGE_B2(Bs0, it0 + 2);
    COMPUTE_B(Bs1, 64);
    __syncthreads();
    // step it0+2: consume Bs0, stage it0+3 -> Bs1
    STAGE_B2(Bs1, it0 + 3);
    COMPUTE_B(Bs0, 128);
    __syncthreads();
    // step it0+3: consume Bs1, stage it0+4 -> Bs0 (if any)
    if (ns < 3) STAGE_B2(Bs0, it0 + 4);
    COMPUTE_B(Bs1, 192);
    __syncthreads();
    // epilogue: pi-packed full-line stores (pad rows written too; never read)
#pragma unroll
    for (int mi = 0; mi < 2; ++mi) {
#pragma unroll
      for (int i = 0; i < 4; ++i) {
        const int row = wr * 32 + mi * 16 + (lane >> 4) * 4 + i;
        u16x8 wv;
#pragma unroll
        for (int ni = 0; ni < 8; ++ni) wv[ni] = f2bf(acc2[mi][ni][i]);
        *(u16x8*)(part + (size_t)(goff + row) * 1024 + ns * 256 + wc * 128 + c16 * 8) = wv;
      }
    }
  }
#undef STAGE_A
#undef STAGE_B1
#undef STAGE_B2
#undef COMPUTE_A
#undef COMPUTE_B
}

// ---------------- reduce: out[tok][c] = b2[c] + sum_s part_c[inv[tok][s]][sigma(c)] ----------------
__global__ __launch_bounds__(256) void k_reduce(const unsigned short* __restrict__ part,
                                                const unsigned* __restrict__ inv,
                                                const float* __restrict__ b2,
                                                float* __restrict__ out) {
  __shared__ float lds[8 * 1028];  // 8 tokens x 1024 (+4 pad)
  const int tid = threadIdx.x;
  const int tok0 = blockIdx.x * 8;
  const int tok_l = tid >> 5;
  const int l32 = tid & 31;

  const uint4 iv = *(const uint4*)(inv + (size_t)(tok0 + tok_l) * 4);
  const unsigned prow[4] = {iv.x, iv.y, iv.z, iv.w};

#pragma unroll
  for (int g = 0; g < 4; ++g) {
    const int idx = g * 32 + l32;          // p-group in [0,128)
    const int p0 = idx * 8;
    float s[8] = {0.f, 0.f, 0.f, 0.f, 0.f, 0.f, 0.f, 0.f};
#pragma unroll
    for (int sl = 0; sl < 4; ++sl) {
      u16x8 v = *(const u16x8*)(part + (size_t)prow[sl] * 1024 + p0);
#pragma unroll
      for (int j = 0; j < 8; ++j)
        s[j] += __uint_as_float((unsigned)(unsigned short)v[j] << 16);
    }
    const int ns = idx >> 5, wcb = (idx >> 4) & 1, cc = idx & 15;
#pragma unroll
    for (int ni = 0; ni < 8; ++ni)
      lds[tok_l * 1028 + ns * 256 + wcb * 128 + ni * 16 + cc] = s[ni];
  }
  __syncthreads();
  // write out coalesced, one token-row per round
  const float4 b2v = ((const float4*)b2)[tid];
#pragma unroll
  for (int r = 0; r < 8; ++r) {
    f32x4 lv = *(f32x4*)&lds[r * 1028 + tid * 4];
    float4 o = make_float4(lv[0] + b2v.x, lv[1] + b2v.y, lv[2] + b2v.z, lv[3] + b2v.w);
    *(float4*)(out + (size_t)(tok0 + r) * 1024 + tid * 4) = o;
  }
}

extern "C" void kernel_launch(void* const* d_in, const int* in_sizes, int n_in,
                              void* d_out, int out_size, void* d_ws, size_t ws_size,
                              hipStream_t stream) {
  const float* x  = (const float*)d_in[0];
  const float* rw = (const float*)d_in[1];
  const float* rb = (const float*)d_in[2];
  const float* w1 = (const float*)d_in[3];
  const float* b1 = (const float*)d_in[4];
  const float* w2 = (const float*)d_in[5];
  const float* b2 = (const float*)d_in[6];
  float* out = (float*)d_out;

  char* ws = (char*)d_ws;
  unsigned short* part = (unsigned short*)(ws);              // 138,412,032 B
  unsigned short* xb   = (unsigned short*)(ws + 138412032);  //  33,554,432 B
  unsigned short* w1b  = (unsigned short*)(ws + 171966464);  //   8,388,608 B
  unsigned short* w2p  = (unsigned short*)(ws + 180355072);  //   8,388,608 B
  unsigned* tokb       = (unsigned*)(ws + 188743680);        //      65,536 B
  unsigned short* list = (unsigned short*)(ws + 188809216);  //     135,168 B
  unsigned* inv        = (unsigned*)(ws + 188944384);        //     262,144 B
  float* b1p           = (float*)(ws + 189206528);           //      16,384 B
  unsigned* counts     = (unsigned*)(ws + 189222912);
  unsigned* off        = (unsigned*)(ws + 189222976);
  unsigned* cursors    = (unsigned*)(ws + 189223104);

  k_zero<<<dim3(133), dim3(256), 0, stream>>>((unsigned*)list, counts);
  k_convert<<<dim3(1024), dim3(256), 0, stream>>>(w1, w2, b1, w1b, w2p, b1p);
  k_router<<<dim3(512), dim3(256), 0, stream>>>(x, rw, rb, tokb, counts, xb);
  k_scan<<<dim3(1), dim3(64), 0, stream>>>(counts, off, cursors);
  k_build<<<dim3(64), dim3(256), 0, stream>>>(tokb, cursors, list, inv);
  k_ffn<<<dim3(2048), dim3(512), 0, stream>>>(xb, w1b, w2p, b1p, list, counts, off, part);
  k_reduce<<<dim3(2048), dim3(256), 0, stream>>>(part, inv, b2, out);
}